// Round 1
// baseline (1672.625 us; speedup 1.0000x reference)
//
#include <hip/hip_runtime.h>
#include <stdint.h>

#define B_DIM 4096
#define DIN   4096
#define E_DIM 2048
#define H_DIM 2048
#define V_DIM 32000

typedef __attribute__((ext_vector_type(8))) short s8v;     // 8 x bf16 (MFMA A/B frag)
typedef __attribute__((ext_vector_type(4))) float f4v;     // MFMA C/D frag

__device__ __forceinline__ ushort f2bf(float f) {
    union { float f; uint32_t u; } v; v.f = f;
    uint32_t u = v.u;
    return (ushort)((u + 0x7FFFu + ((u >> 16) & 1u)) >> 16);
}
__device__ __forceinline__ float bf2f(ushort h) {
    union { uint32_t u; float f; } v; v.u = ((uint32_t)h) << 16;
    return v.f;
}

// ---------------- fp32 -> bf16 plain convert (input matrix) ----------------
__global__ void k_cvt(const float* __restrict__ src, ushort* __restrict__ dst, int n4) {
    int i = blockIdx.x * blockDim.x + threadIdx.x;   // one float4 per thread
    if (i >= n4) return;
    float4 v = *(const float4*)(src + (size_t)i * 4);
    ushort4 o;
    o.x = f2bf(v.x); o.y = f2bf(v.y); o.z = f2bf(v.z); o.w = f2bf(v.w);
    *(ushort4*)(dst + (size_t)i * 4) = o;
}

// hidden [4096][2048] fp32 -> A2 right half (row stride 4096, col offset 2048)
__global__ void k_cvt_hidden(const float* __restrict__ src, ushort* __restrict__ dst) {
    int i = blockIdx.x * blockDim.x + threadIdx.x;   // per 4 elements
    int b = i >> 9;            // 512 float4-chunks per row
    int c = (i & 511) << 2;
    float4 v = *(const float4*)(src + (size_t)b * H_DIM + c);
    ushort4 o;
    o.x = f2bf(v.x); o.y = f2bf(v.y); o.z = f2bf(v.z); o.w = f2bf(v.w);
    *(ushort4*)(dst + (size_t)b * 4096 + 2048 + c) = o;
}

// ---------------- transpose + convert: src fp32 [K x N] -> dst bf16 [N x K] ----------------
__global__ void k_transpose_bf16(const float* __restrict__ src, ushort* __restrict__ dst,
                                 int srcCols, int dstStride, int dstRowOff, int dstColOff) {
    __shared__ float tile[32][33];
    int tx = threadIdx.x, ty = threadIdx.y;
    int n0 = blockIdx.x * 32, k0 = blockIdx.y * 32;
#pragma unroll
    for (int i = 0; i < 4; i++)
        tile[ty + 8 * i][tx] = src[(size_t)(k0 + ty + 8 * i) * srcCols + n0 + tx];
    __syncthreads();
#pragma unroll
    for (int i = 0; i < 4; i++) {
        int n = ty + 8 * i;
        dst[(size_t)(dstRowOff + n0 + n) * dstStride + dstColOff + k0 + tx] = f2bf(tile[tx][n]);
    }
}

// ---------------- pack gate biases: bias2[g*2048+h] = b_g[h] + bh_g[h] ----------------
__global__ void k_biaspack(const float* __restrict__ b0, const float* __restrict__ bh0,
                           const float* __restrict__ b1, const float* __restrict__ bh1,
                           const float* __restrict__ b2, const float* __restrict__ bh2,
                           const float* __restrict__ b3, const float* __restrict__ bh3,
                           float* __restrict__ out) {
    int h = blockIdx.x * blockDim.x + threadIdx.x;
    if (h >= H_DIM) return;
    out[h]              = b0[h] + bh0[h];
    out[H_DIM + h]      = b1[h] + bh1[h];
    out[2 * H_DIM + h]  = b2[h] + bh2[h];
    out[3 * H_DIM + h]  = b3[h] + bh3[h];
}

// ---------------- bf16 GEMM: C[M,N] = A[M,K] @ Bt[N,K]^T + bias[N] ----------------
// 128x128 tile, BK=64, 256 threads = 4 waves (2x2 of 64x64), global_load_lds width-16,
// 16x16x32 bf16 MFMA, fp32 accum. m97-class 2-phase structure, linear LDS.
template<int OUT_BF16>
__global__ __launch_bounds__(256, 2)
void k_gemm_bt(const ushort* __restrict__ A, const ushort* __restrict__ Bt,
               void* __restrict__ Cv, const float* __restrict__ bias,
               int M, int N, int K, int lda, int ldb, int ldc) {
    __shared__ __align__(16) ushort ldsA[128 * 64];
    __shared__ __align__(16) ushort ldsB[128 * 64];
    const int t = threadIdx.x;
    const int wid = t >> 6, lane = t & 63;

    // XCD-aware swizzle (all grids are %8 == 0)
    int nwg = gridDim.x;
    int bid = blockIdx.x;
    int wg  = (bid & 7) * (nwg >> 3) + (bid >> 3);
    int NT  = N >> 7;
    int mt  = wg / NT, nt = wg - mt * NT;
    int m0  = mt << 7, n0 = nt << 7;

    f4v acc[4][4];
#pragma unroll
    for (int i = 0; i < 4; i++)
#pragma unroll
        for (int j = 0; j < 4; j++) acc[i][j] = (f4v){0.f, 0.f, 0.f, 0.f};

    const int wr = wid >> 1, wc = wid & 1;     // wave -> 64x64 quadrant

    const int kTiles = K >> 6;
    for (int kt = 0; kt < kTiles; ++kt) {
        // ---- stage A,B tiles (128x64 bf16 each) via global_load_lds, linear layout ----
#pragma unroll
        for (int c = 0; c < 4; ++c) {
            int idx = c * 256 + wid * 64 + lane;        // 16B chunk index
            int row = idx >> 3;                          // 8 chunks per 128B row
            int kb  = (idx & 7) << 4;                    // byte offset within row
            const ushort* gA = A  + (size_t)(m0 + row) * lda + (kt << 6) + (kb >> 1);
            const ushort* gB = Bt + (size_t)(n0 + row) * ldb + (kt << 6) + (kb >> 1);
            char* lA = (char*)ldsA + (size_t)(c * 256 + wid * 64) * 16;  // wave-uniform base
            char* lB = (char*)ldsB + (size_t)(c * 256 + wid * 64) * 16;
            __builtin_amdgcn_global_load_lds((const __attribute__((address_space(1))) void*)gA,
                                             (__attribute__((address_space(3))) void*)lA, 16, 0, 0);
            __builtin_amdgcn_global_load_lds((const __attribute__((address_space(1))) void*)gB,
                                             (__attribute__((address_space(3))) void*)lB, 16, 0, 0);
        }
        __syncthreads();   // drains vmcnt before barrier

        // ---- compute: 2 k-steps of K=32, 4x4 fragment tiles per wave ----
#pragma unroll
        for (int ks = 0; ks < 2; ++ks) {
            s8v af[4], bfr[4];
#pragma unroll
            for (int m = 0; m < 4; ++m) {
                int r = wr * 64 + m * 16 + (lane & 15);
                int kb = ks * 64 + ((lane >> 4) << 4);
                af[m] = *(const s8v*)((const char*)ldsA + r * 128 + kb);
            }
#pragma unroll
            for (int n = 0; n < 4; ++n) {
                int r = wc * 64 + n * 16 + (lane & 15);
                int kb = ks * 64 + ((lane >> 4) << 4);
                bfr[n] = *(const s8v*)((const char*)ldsB + r * 128 + kb);
            }
#pragma unroll
            for (int m = 0; m < 4; ++m)
#pragma unroll
                for (int n = 0; n < 4; ++n)
                    acc[m][n] = __builtin_amdgcn_mfma_f32_16x16x32_bf16(af[m], bfr[n], acc[m][n], 0, 0, 0);
        }
        __syncthreads();   // all waves done reading before next stage overwrites
    }

    // ---- epilogue: C[row=(lane>>4)*4+reg][col=lane&15] per 16x16 frag ----
#pragma unroll
    for (int n = 0; n < 4; ++n) {
        int cg = n0 + wc * 64 + n * 16 + (lane & 15);
        float bv = bias[cg];
#pragma unroll
        for (int m = 0; m < 4; ++m) {
            int rbase = m0 + wr * 64 + m * 16 + ((lane >> 4) << 2);
#pragma unroll
            for (int r = 0; r < 4; ++r) {
                float v = acc[m][n][r] + bv;
                if (OUT_BF16)
                    ((ushort*)Cv)[(size_t)(rbase + r) * ldc + cg] = f2bf(v);
                else
                    ((float*)Cv)[(size_t)(rbase + r) * ldc + cg] = v;
            }
        }
    }
}

// ---------------- LSTM elementwise: gates -> new_cell, new_hidden ----------------
__global__ void k_lstm_cell(const float* __restrict__ G, const float* __restrict__ cell,
                            float* __restrict__ outH, float* __restrict__ outC,
                            ushort* __restrict__ hidBf) {
    int i = blockIdx.x * blockDim.x + threadIdx.x;   // B*H elements
    int b = i >> 11;            // H = 2048
    int h = i & 2047;
    const float* g = G + (size_t)b * (4 * H_DIM);
    float pf = g[h], pi = g[H_DIM + h], pc = g[2 * H_DIM + h], po = g[3 * H_DIM + h];
    float f  = 1.f / (1.f + __expf(-pf));
    float ii = 1.f / (1.f + __expf(-pi));
    float gg = tanhf(pc);
    float oo = 1.f / (1.f + __expf(-po));
    float nc = f * cell[i] + ii * gg;
    float nh = oo * tanhf(nc);
    outC[i] = nc;
    outH[i] = nh;
    hidBf[i] = f2bf(nh);
}

// ---------------- row logsumexp over V=32000 (fp32 logits in d_out) ----------------
__global__ void k_rowstats(const float* __restrict__ logits, float* __restrict__ lse) {
    int b = blockIdx.x;
    const float* row = logits + (size_t)b * V_DIM;
    int t = threadIdx.x;
    float m = -1e30f, s = 0.f;
    for (int c = t; c < V_DIM / 4; c += 256) {
        float4 v = *(const float4*)(row + c * 4);
        float xs[4] = {v.x, v.y, v.z, v.w};
#pragma unroll
        for (int j = 0; j < 4; ++j) {
            float x = xs[j];
            float nm = fmaxf(m, x);
            s = s * __expf(m - nm) + __expf(x - nm);
            m = nm;
        }
    }
#pragma unroll
    for (int off = 1; off < 64; off <<= 1) {
        float mo = __shfl_xor(m, off);
        float so = __shfl_xor(s, off);
        float nm = fmaxf(m, mo);
        s = s * __expf(m - nm) + so * __expf(mo - nm);
        m = nm;
    }
    __shared__ float ms[4], ss[4];
    int wid = t >> 6;
    if ((t & 63) == 0) { ms[wid] = m; ss[wid] = s; }
    __syncthreads();
    if (t == 0) {
        float M = ms[0], S = ss[0];
#pragma unroll
        for (int w = 1; w < 4; ++w) {
            float nm = fmaxf(M, ms[w]);
            S = S * __expf(M - nm) + ss[w] * __expf(ms[w] - nm);
            M = nm;
        }
        lse[b] = M + __logf(S);
    }
}

// ---------------- in-place normalize: out = logit - lse[row] ----------------
__global__ void k_norm(float* __restrict__ out, const float* __restrict__ lse) {
    int i = blockIdx.x * blockDim.x + threadIdx.x;   // per 4 floats
    int b = i / (V_DIM / 4);
    int c = (i - b * (V_DIM / 4)) * 4;
    float l = lse[b];
    float* p = out + (size_t)b * V_DIM + c;
    float4 v = *(const float4*)p;
    v.x -= l; v.y -= l; v.z -= l; v.w -= l;
    *(float4*)p = v;
}

extern "C" void kernel_launch(void* const* d_in, const int* in_sizes, int n_in,
                              void* d_out, int out_size, void* d_ws, size_t ws_size,
                              hipStream_t stream) {
    const float* in_input  = (const float*)d_in[0];
    const float* in_hidden = (const float*)d_in[1];
    const float* in_cell   = (const float*)d_in[2];
    const float* We   = (const float*)d_in[3];
    const float* be   = (const float*)d_in[4];
    const float* Wf   = (const float*)d_in[5];
    const float* bfv  = (const float*)d_in[6];
    const float* Wi   = (const float*)d_in[7];
    const float* biv  = (const float*)d_in[8];
    const float* Wc   = (const float*)d_in[9];
    const float* bcv  = (const float*)d_in[10];
    const float* Wo   = (const float*)d_in[11];
    const float* bov  = (const float*)d_in[12];
    const float* Uf   = (const float*)d_in[13];
    const float* bhf  = (const float*)d_in[14];
    const float* Ui   = (const float*)d_in[15];
    const float* bhi  = (const float*)d_in[16];
    const float* Uc   = (const float*)d_in[17];
    const float* bhc  = (const float*)d_in[18];
    const float* Uo   = (const float*)d_in[19];
    const float* bho  = (const float*)d_in[20];
    const float* Wend = (const float*)d_in[21];
    const float* bend = (const float*)d_in[22];

    char* ws = (char*)d_ws;
    // -------- workspace layout (bytes) --------
    const size_t oWendT = 0;                                   // 32000*2048*2 = 131,072,000
    const size_t oHidBf = oWendT + (size_t)V_DIM * H_DIM * 2;  // 16,777,216
    const size_t oBias2 = oHidBf + (size_t)B_DIM * H_DIM * 2;  // 32,768
    const size_t oLse   = oBias2 + 4 * H_DIM * 4;              // 16,384
    const size_t oBig   = oLse + B_DIM * 4;
    // phase-overlapped region: [Ain][WeT][A2][WUT][G]; all dead before head GEMM
    const size_t oAin = oBig;                                   // 4096*4096*2 = 33,554,432
    const size_t oWeT = oAin + (size_t)B_DIM * DIN * 2;         // 2048*4096*2 = 16,777,216
    const size_t oA2  = oWeT + (size_t)E_DIM * DIN * 2;         // 4096*4096*2 = 33,554,432
    const size_t oWUT = oA2  + (size_t)B_DIM * 4096 * 2;        // 8192*4096*2 = 67,108,864
    const size_t oG   = oWUT + (size_t)8192 * 4096 * 2;         // 4096*8192*4 = 134,217,728

    ushort* WendT = (ushort*)(ws + oWendT);
    ushort* hidBf = (ushort*)(ws + oHidBf);
    float*  bias2 = (float*)(ws + oBias2);
    float*  lse   = (float*)(ws + oLse);
    ushort* Ain   = (ushort*)(ws + oAin);
    ushort* WeT   = (ushort*)(ws + oWeT);
    ushort* A2    = (ushort*)(ws + oA2);
    ushort* WUT   = (ushort*)(ws + oWUT);
    float*  G     = (float*)(ws + oG);

    float* out  = (float*)d_out;
    float* outH = out + (size_t)B_DIM * V_DIM;
    float* outC = outH + (size_t)B_DIM * H_DIM;

    dim3 blk256(256);

    // P0: convert input + hidden, transpose all weights, pack biases
    k_cvt<<<dim3((B_DIM * DIN / 4) / 256), blk256, 0, stream>>>(in_input, Ain, B_DIM * DIN / 4);
    k_cvt_hidden<<<dim3((B_DIM * H_DIM / 4) / 256), blk256, 0, stream>>>(in_hidden, A2);

    dim3 tb(32, 8);
    k_transpose_bf16<<<dim3(E_DIM / 32, DIN / 32), tb, 0, stream>>>(We, WeT, E_DIM, DIN, 0, 0);
    k_transpose_bf16<<<dim3(H_DIM / 32, E_DIM / 32), tb, 0, stream>>>(Wf, WUT, H_DIM, 4096, 0,        0);
    k_transpose_bf16<<<dim3(H_DIM / 32, E_DIM / 32), tb, 0, stream>>>(Wi, WUT, H_DIM, 4096, H_DIM,    0);
    k_transpose_bf16<<<dim3(H_DIM / 32, E_DIM / 32), tb, 0, stream>>>(Wc, WUT, H_DIM, 4096, 2 * H_DIM, 0);
    k_transpose_bf16<<<dim3(H_DIM / 32, E_DIM / 32), tb, 0, stream>>>(Wo, WUT, H_DIM, 4096, 3 * H_DIM, 0);
    k_transpose_bf16<<<dim3(H_DIM / 32, H_DIM / 32), tb, 0, stream>>>(Uf, WUT, H_DIM, 4096, 0,        2048);
    k_transpose_bf16<<<dim3(H_DIM / 32, H_DIM / 32), tb, 0, stream>>>(Ui, WUT, H_DIM, 4096, H_DIM,    2048);
    k_transpose_bf16<<<dim3(H_DIM / 32, H_DIM / 32), tb, 0, stream>>>(Uc, WUT, H_DIM, 4096, 2 * H_DIM, 2048);
    k_transpose_bf16<<<dim3(H_DIM / 32, H_DIM / 32), tb, 0, stream>>>(Uo, WUT, H_DIM, 4096, 3 * H_DIM, 2048);
    k_transpose_bf16<<<dim3(V_DIM / 32, H_DIM / 32), tb, 0, stream>>>(Wend, WendT, V_DIM, H_DIM, 0, 0);
    k_biaspack<<<dim3(H_DIM / 256), blk256, 0, stream>>>(bfv, bhf, biv, bhi, bcv, bhc, bov, bho, bias2);

    // P1: emb = input @ We + be  -> A2 left half (bf16)
    k_gemm_bt<1><<<dim3((B_DIM / 128) * (E_DIM / 128)), blk256, 0, stream>>>(
        Ain, WeT, A2, be, B_DIM, E_DIM, DIN, DIN, DIN, 4096);

    // P2: gates = [emb|hidden] @ [W;U] + (b+bh)  -> G fp32
    k_gemm_bt<0><<<dim3((B_DIM / 128) * (8192 / 128)), blk256, 0, stream>>>(
        A2, WUT, G, bias2, B_DIM, 8192, 4096, 4096, 4096, 8192);

    // P3: elementwise LSTM cell
    k_lstm_cell<<<dim3(B_DIM * H_DIM / 256), blk256, 0, stream>>>(G, in_cell, outH, outC, hidBf);

    // P4: logits = new_hidden @ Wend + bend -> d_out (fp32)
    k_gemm_bt<0><<<dim3((B_DIM / 128) * (V_DIM / 128)), blk256, 0, stream>>>(
        hidBf, WendT, out, bend, B_DIM, V_DIM, H_DIM, H_DIM, H_DIM, V_DIM);

    // P5: log_softmax
    k_rowstats<<<dim3(B_DIM), blk256, 0, stream>>>(out, lse);
    k_norm<<<dim3(B_DIM * (V_DIM / 4) / 256), blk256, 0, stream>>>(out, lse);
}

// Round 2
// 1627.653 us; speedup vs baseline: 1.0276x; 1.0276x over previous
//
#include <hip/hip_runtime.h>
#include <stdint.h>

#define B_DIM 4096
#define DIN   4096
#define E_DIM 2048
#define H_DIM 2048
#define V_DIM 32000

typedef __attribute__((ext_vector_type(8))) short s8v;     // 8 x bf16 (MFMA A/B frag)
typedef __attribute__((ext_vector_type(4))) float f4v;     // MFMA C/D frag

__device__ __forceinline__ ushort f2bf(float f) {
    union { float f; uint32_t u; } v; v.f = f;
    uint32_t u = v.u;
    return (ushort)((u + 0x7FFFu + ((u >> 16) & 1u)) >> 16);
}

// ---------------- fp32 -> bf16 plain convert (input matrix) ----------------
__global__ void k_cvt(const float* __restrict__ src, ushort* __restrict__ dst, int n4) {
    int i = blockIdx.x * blockDim.x + threadIdx.x;
    if (i >= n4) return;
    float4 v = *(const float4*)(src + (size_t)i * 4);
    ushort4 o;
    o.x = f2bf(v.x); o.y = f2bf(v.y); o.z = f2bf(v.z); o.w = f2bf(v.w);
    *(ushort4*)(dst + (size_t)i * 4) = o;
}

// hidden [4096][2048] fp32 -> A2 right half (row stride 4096, col offset 2048)
__global__ void k_cvt_hidden(const float* __restrict__ src, ushort* __restrict__ dst) {
    int i = blockIdx.x * blockDim.x + threadIdx.x;
    int b = i >> 9;
    int c = (i & 511) << 2;
    float4 v = *(const float4*)(src + (size_t)b * H_DIM + c);
    ushort4 o;
    o.x = f2bf(v.x); o.y = f2bf(v.y); o.z = f2bf(v.z); o.w = f2bf(v.w);
    *(ushort4*)(dst + (size_t)b * 4096 + 2048 + c) = o;
}

// ---------------- transpose + convert: src fp32 [K x N] -> dst bf16 [N x K] ----------------
__global__ void k_transpose_bf16(const float* __restrict__ src, ushort* __restrict__ dst,
                                 int srcCols, int dstStride, int dstRowOff, int dstColOff) {
    __shared__ float tile[32][33];
    int tx = threadIdx.x, ty = threadIdx.y;
    int n0 = blockIdx.x * 32, k0 = blockIdx.y * 32;
#pragma unroll
    for (int i = 0; i < 4; i++)
        tile[ty + 8 * i][tx] = src[(size_t)(k0 + ty + 8 * i) * srcCols + n0 + tx];
    __syncthreads();
#pragma unroll
    for (int i = 0; i < 4; i++) {
        int n = ty + 8 * i;
        dst[(size_t)(dstRowOff + n0 + n) * dstStride + dstColOff + k0 + tx] = f2bf(tile[tx][n]);
    }
}

// gate-interleaved transpose: W_g column h -> WUT row (h>>4)*64 + g*16 + (h&15)
__global__ void k_transpose_gate(const float* __restrict__ src, ushort* __restrict__ dst,
                                 int g, int dstColOff) {
    __shared__ float tile[32][33];
    int tx = threadIdx.x, ty = threadIdx.y;
    int n0 = blockIdx.x * 32, k0 = blockIdx.y * 32;
#pragma unroll
    for (int i = 0; i < 4; i++)
        tile[ty + 8 * i][tx] = src[(size_t)(k0 + ty + 8 * i) * H_DIM + n0 + tx];
    __syncthreads();
#pragma unroll
    for (int i = 0; i < 4; i++) {
        int nn = n0 + ty + 8 * i;
        int drow = ((nn >> 4) << 6) + (g << 4) + (nn & 15);
        dst[(size_t)drow * 4096 + dstColOff + k0 + tx] = f2bf(tile[tx][ty + 8 * i]);
    }
}

// pack gate biases into the gate-interleaved layout
__global__ void k_biaspack(const float* __restrict__ b0, const float* __restrict__ bh0,
                           const float* __restrict__ b1, const float* __restrict__ bh1,
                           const float* __restrict__ b2, const float* __restrict__ bh2,
                           const float* __restrict__ b3, const float* __restrict__ bh3,
                           float* __restrict__ out) {
    int h = blockIdx.x * blockDim.x + threadIdx.x;
    if (h >= H_DIM) return;
    int base = ((h >> 4) << 6) + (h & 15);
    out[base]      = b0[h] + bh0[h];
    out[base + 16] = b1[h] + bh1[h];
    out[base + 32] = b2[h] + bh2[h];
    out[base + 48] = b3[h] + bh3[h];
}

// ---------------- 128x128 2-phase GEMM (kept for emb: grid 512 fills GPU) ----------------
template<int OUT_BF16>
__global__ __launch_bounds__(256, 2)
void k_gemm_bt(const ushort* __restrict__ A, const ushort* __restrict__ Bt,
               void* __restrict__ Cv, const float* __restrict__ bias,
               int M, int N, int K, int lda, int ldb, int ldc) {
    __shared__ __align__(16) ushort ldsA[128 * 64];
    __shared__ __align__(16) ushort ldsB[128 * 64];
    const int t = threadIdx.x;
    const int wid = t >> 6, lane = t & 63;

    int nwg = gridDim.x;
    int bid = blockIdx.x;
    int wg  = (bid & 7) * (nwg >> 3) + (bid >> 3);
    int NT  = N >> 7;
    int mt  = wg / NT, nt = wg - mt * NT;
    int m0  = mt << 7, n0 = nt << 7;

    f4v acc[4][4];
#pragma unroll
    for (int i = 0; i < 4; i++)
#pragma unroll
        for (int j = 0; j < 4; j++) acc[i][j] = (f4v){0.f, 0.f, 0.f, 0.f};

    const int wr = wid >> 1, wc = wid & 1;

    const int kTiles = K >> 6;
    for (int kt = 0; kt < kTiles; ++kt) {
#pragma unroll
        for (int c = 0; c < 4; ++c) {
            int idx = c * 256 + wid * 64 + lane;
            int row = idx >> 3;
            int kb  = (idx & 7) << 4;
            const ushort* gA = A  + (size_t)(m0 + row) * lda + (kt << 6) + (kb >> 1);
            const ushort* gB = Bt + (size_t)(n0 + row) * ldb + (kt << 6) + (kb >> 1);
            char* lA = (char*)ldsA + (size_t)(c * 256 + wid * 64) * 16;
            char* lB = (char*)ldsB + (size_t)(c * 256 + wid * 64) * 16;
            __builtin_amdgcn_global_load_lds((const __attribute__((address_space(1))) void*)gA,
                                             (__attribute__((address_space(3))) void*)lA, 16, 0, 0);
            __builtin_amdgcn_global_load_lds((const __attribute__((address_space(1))) void*)gB,
                                             (__attribute__((address_space(3))) void*)lB, 16, 0, 0);
        }
        __syncthreads();

#pragma unroll
        for (int ks = 0; ks < 2; ++ks) {
            s8v af[4], bfr[4];
#pragma unroll
            for (int m = 0; m < 4; ++m) {
                int r = wr * 64 + m * 16 + (lane & 15);
                int kb = ks * 64 + ((lane >> 4) << 4);
                af[m] = *(const s8v*)((const char*)ldsA + r * 128 + kb);
            }
#pragma unroll
            for (int n = 0; n < 4; ++n) {
                int r = wc * 64 + n * 16 + (lane & 15);
                int kb = ks * 64 + ((lane >> 4) << 4);
                bfr[n] = *(const s8v*)((const char*)ldsB + r * 128 + kb);
            }
#pragma unroll
            for (int m = 0; m < 4; ++m)
#pragma unroll
                for (int n = 0; n < 4; ++n)
                    acc[m][n] = __builtin_amdgcn_mfma_f32_16x16x32_bf16(af[m], bfr[n], acc[m][n], 0, 0, 0);
        }
        __syncthreads();
    }

#pragma unroll
    for (int n = 0; n < 4; ++n) {
        int cg = n0 + wc * 64 + n * 16 + (lane & 15);
        float bv = bias[cg];
#pragma unroll
        for (int m = 0; m < 4; ++m) {
            int rbase = m0 + wr * 64 + m * 16 + ((lane >> 4) << 2);
#pragma unroll
            for (int r = 0; r < 4; ++r) {
                float v = acc[m][n][r] + bv;
                if (OUT_BF16)
                    ((ushort*)Cv)[(size_t)(rbase + r) * ldc + cg] = f2bf(v);
                else
                    ((float*)Cv)[(size_t)(rbase + r) * ldc + cg] = v;
            }
        }
    }
}

// ---------------- 256x256 8-phase GEMM, BK=64, 8 waves (2Mx4N), counted vmcnt ----------------
// EPI: 0 = fp32 + bias, 2 = fused LSTM cell (gate-interleaved N layout)
template<int EPI>
__global__ __launch_bounds__(512, 2)
void k_gemm256(const ushort* __restrict__ A, const ushort* __restrict__ Bt,
               void* __restrict__ Cv, const float* __restrict__ bias,
               int N, int K, int lda, int ldb, int ldc,
               const float* __restrict__ cell, float* __restrict__ outH,
               float* __restrict__ outC, ushort* __restrict__ hidBf) {
    __shared__ __align__(16) ushort ldsA[2][256 * 64];   // 64 KB
    __shared__ __align__(16) ushort ldsB[2][256 * 64];   // 64 KB
    const int t = threadIdx.x;
    const int wid = t >> 6, lane = t & 63;
    const int wr = wid >> 2, wc = wid & 3;     // 2 x 4 waves, each owns 128x64 output

    int nwg = gridDim.x, bid = blockIdx.x;
    int wg = (bid & 7) * (nwg >> 3) + (bid >> 3);
    int NT = N >> 8;
    int mt = wg / NT, nt = wg - mt * NT;
    int m0 = mt << 8, n0 = nt << 8;

    // staging geometry: idx = c*512+t -> (row, slot); source pre-swizzled (slot ^ row&7)
    int offA[4], offB[4];
#pragma unroll
    for (int c = 0; c < 4; ++c) {
        int idx = c * 512 + t;
        int row = idx >> 3;
        int col = ((idx & 7) ^ (row & 7)) << 3;
        offA[c] = (m0 + row) * lda + col;
        offB[c] = (n0 + row) * ldb + col;
    }

#define STAGE_TILE(BUFSEL, KTILE) do {                                                   \
    const int kb_ = (KTILE) << 6;                                                        \
    _Pragma("unroll")                                                                    \
    for (int c = 0; c < 4; ++c) {                                                        \
        const ushort* gA = A  + offA[c] + kb_;                                           \
        const ushort* gB = Bt + offB[c] + kb_;                                           \
        ushort* lA = &ldsA[BUFSEL][(c * 512 + (wid << 6)) * 8];                          \
        ushort* lB = &ldsB[BUFSEL][(c * 512 + (wid << 6)) * 8];                          \
        __builtin_amdgcn_global_load_lds((const __attribute__((address_space(1))) void*)gA, \
                                         (__attribute__((address_space(3))) void*)lA, 16, 0, 0); \
        __builtin_amdgcn_global_load_lds((const __attribute__((address_space(1))) void*)gB, \
                                         (__attribute__((address_space(3))) void*)lB, 16, 0, 0); \
    } } while (0)

    f4v acc[8][4];
#pragma unroll
    for (int i = 0; i < 8; i++)
#pragma unroll
        for (int j = 0; j < 4; j++) acc[i][j] = (f4v){0.f, 0.f, 0.f, 0.f};

    s8v af[4][2], bfA[2][2], bfB[2][2];
    const int swz = (lane & 7) << 4;                 // read-side XOR (row&7 == lane&7)
    const int kcol = (lane >> 4) << 4;               // 16B k-slot within 64B k-half

#define LOAD_AF(BUF, MH) do {                                                            \
    _Pragma("unroll")                                                                    \
    for (int m = 0; m < 4; ++m) {                                                        \
        int row = wr * 128 + (MH) * 64 + m * 16 + (lane & 15);                           \
        _Pragma("unroll")                                                                \
        for (int ks = 0; ks < 2; ++ks)                                                   \
            af[m][ks] = *(const s8v*)((const char*)&ldsA[BUF][0] + row * 128 + ((ks * 64 + kcol) ^ swz)); \
    } } while (0)

#define LOAD_BF(BUF, NH, DST) do {                                                       \
    _Pragma("unroll")                                                                    \
    for (int n = 0; n < 2; ++n) {                                                        \
        int row = wc * 64 + (NH) * 32 + n * 16 + (lane & 15);                            \
        _Pragma("unroll")                                                                \
        for (int ks = 0; ks < 2; ++ks)                                                   \
            DST[n][ks] = *(const s8v*)((const char*)&ldsB[BUF][0] + row * 128 + ((ks * 64 + kcol) ^ swz)); \
    } } while (0)

#define DO_MFMA(MH, NH, BFR) do {                                                        \
    __builtin_amdgcn_s_setprio(1);                                                       \
    _Pragma("unroll")                                                                    \
    for (int m = 0; m < 4; ++m)                                                          \
    _Pragma("unroll")                                                                    \
    for (int n = 0; n < 2; ++n)                                                          \
    _Pragma("unroll")                                                                    \
    for (int ks = 0; ks < 2; ++ks)                                                       \
        acc[(MH) * 4 + m][(NH) * 2 + n] =                                                \
            __builtin_amdgcn_mfma_f32_16x16x32_bf16(af[m][ks], BFR[n][ks],               \
                                                    acc[(MH) * 4 + m][(NH) * 2 + n], 0, 0, 0); \
    __builtin_amdgcn_s_setprio(0);                                                       \
} while (0)

#define PBAR() do { asm volatile("" ::: "memory"); __builtin_amdgcn_s_barrier();         \
                    asm volatile("" ::: "memory"); } while (0)

    // prologue: tiles 0 and 1 in flight (16 loads)
    STAGE_TILE(0, 0);
    STAGE_TILE(1, 1);

    const int kTiles = K >> 6;
    for (int kt = 0; kt < kTiles; ++kt) {
        const int buf = kt & 1;
        // -------- phase 0: wait THIS tile's 8 loads (next tile's 8 stay in flight) --------
        if (kt + 1 < kTiles) asm volatile("s_waitcnt vmcnt(8)" ::: "memory");
        else                 asm volatile("s_waitcnt vmcnt(0)" ::: "memory");
        __builtin_amdgcn_s_barrier();
        __builtin_amdgcn_sched_barrier(0);
        LOAD_AF(buf, 0);
        LOAD_BF(buf, 0, bfA);
        DO_MFMA(0, 0, bfA);
        PBAR();
        // -------- phase 1 --------
        LOAD_BF(buf, 1, bfB);
        DO_MFMA(0, 1, bfB);
        PBAR();
        // -------- phase 2 (last LDS reads of this tile) --------
        LOAD_AF(buf, 1);
        DO_MFMA(1, 1, bfB);
        PBAR();
        // -------- phase 3: pure-register MFMA; prefetch tile kt+2 into this buffer --------
        if (kt + 2 < kTiles) STAGE_TILE(buf, kt + 2);
        DO_MFMA(1, 0, bfA);
        PBAR();
    }

    // ---------------- epilogue ----------------
    if (EPI == 0) {
#pragma unroll
        for (int n = 0; n < 4; ++n) {
            int cg = n0 + wc * 64 + n * 16 + (lane & 15);
            float bv = bias[cg];
#pragma unroll
            for (int m = 0; m < 8; ++m) {
                int rb = m0 + wr * 128 + m * 16 + ((lane >> 4) << 2);
#pragma unroll
                for (int r = 0; r < 4; ++r)
                    ((float*)Cv)[(size_t)(rb + r) * ldc + cg] = acc[m][n][r] + bv;
            }
        }
    } else {
        // gate-interleaved: lane's 4 n-frags are gates f,i,c,o of one h
        int h = (((n0 + wc * 64) >> 6) << 4) + (lane & 15);
        float bv[4];
#pragma unroll
        for (int n = 0; n < 4; ++n) bv[n] = bias[n0 + wc * 64 + n * 16 + (lane & 15)];
#pragma unroll
        for (int m = 0; m < 8; ++m) {
            int rb = m0 + wr * 128 + m * 16 + ((lane >> 4) << 2);
#pragma unroll
            for (int r = 0; r < 4; ++r) {
                int b = rb + r;
                float pf = acc[m][0][r] + bv[0];
                float pi = acc[m][1][r] + bv[1];
                float pc = acc[m][2][r] + bv[2];
                float po = acc[m][3][r] + bv[3];
                float fg = 1.f / (1.f + __expf(-pf));
                float ig = 1.f / (1.f + __expf(-pi));
                float gg = tanhf(pc);
                float og = 1.f / (1.f + __expf(-po));
                size_t off = (size_t)b * H_DIM + h;
                float nc = fg * cell[off] + ig * gg;
                float nh = og * tanhf(nc);
                outC[off] = nc;
                outH[off] = nh;
                hidBf[off] = f2bf(nh);
            }
        }
    }
#undef STAGE_TILE
#undef LOAD_AF
#undef LOAD_BF
#undef DO_MFMA
#undef PBAR
}

// ---------------- row logsumexp over V=32000 ----------------
__global__ void k_rowstats(const float* __restrict__ logits, float* __restrict__ lse) {
    int b = blockIdx.x;
    const float* row = logits + (size_t)b * V_DIM;
    int t = threadIdx.x;
    float m = -1e30f, s = 0.f;
    for (int c = t; c < V_DIM / 4; c += 256) {
        float4 v = *(const float4*)(row + c * 4);
        float xs[4] = {v.x, v.y, v.z, v.w};
#pragma unroll
        for (int j = 0; j < 4; ++j) {
            float x = xs[j];
            float nm = fmaxf(m, x);
            s = s * __expf(m - nm) + __expf(x - nm);
            m = nm;
        }
    }
#pragma unroll
    for (int off = 1; off < 64; off <<= 1) {
        float mo = __shfl_xor(m, off);
        float so = __shfl_xor(s, off);
        float nm = fmaxf(m, mo);
        s = s * __expf(m - nm) + so * __expf(mo - nm);
        m = nm;
    }
    __shared__ float ms[4], ss[4];
    int wid = t >> 6;
    if ((t & 63) == 0) { ms[wid] = m; ss[wid] = s; }
    __syncthreads();
    if (t == 0) {
        float M = ms[0], S = ss[0];
#pragma unroll
        for (int w = 1; w < 4; ++w) {
            float nm = fmaxf(M, ms[w]);
            S = S * __expf(M - nm) + ss[w] * __expf(ms[w] - nm);
            M = nm;
        }
        lse[b] = M + __logf(S);
    }
}

__global__ void k_norm(float* __restrict__ out, const float* __restrict__ lse) {
    int i = blockIdx.x * blockDim.x + threadIdx.x;
    int b = i / (V_DIM / 4);
    int c = (i - b * (V_DIM / 4)) * 4;
    float l = lse[b];
    float* p = out + (size_t)b * V_DIM + c;
    float4 v = *(const float4*)p;
    v.x -= l; v.y -= l; v.z -= l; v.w -= l;
    *(float4*)p = v;
}

extern "C" void kernel_launch(void* const* d_in, const int* in_sizes, int n_in,
                              void* d_out, int out_size, void* d_ws, size_t ws_size,
                              hipStream_t stream) {
    const float* in_input  = (const float*)d_in[0];
    const float* in_hidden = (const float*)d_in[1];
    const float* in_cell   = (const float*)d_in[2];
    const float* We   = (const float*)d_in[3];
    const float* be   = (const float*)d_in[4];
    const float* Wf   = (const float*)d_in[5];
    const float* bfv  = (const float*)d_in[6];
    const float* Wi   = (const float*)d_in[7];
    const float* biv  = (const float*)d_in[8];
    const float* Wc   = (const float*)d_in[9];
    const float* bcv  = (const float*)d_in[10];
    const float* Wo   = (const float*)d_in[11];
    const float* bov  = (const float*)d_in[12];
    const float* Uf   = (const float*)d_in[13];
    const float* bhf  = (const float*)d_in[14];
    const float* Ui   = (const float*)d_in[15];
    const float* bhi  = (const float*)d_in[16];
    const float* Uc   = (const float*)d_in[17];
    const float* bhc  = (const float*)d_in[18];
    const float* Uo   = (const float*)d_in[19];
    const float* bho  = (const float*)d_in[20];
    const float* Wend = (const float*)d_in[21];
    const float* bend = (const float*)d_in[22];

    char* ws = (char*)d_ws;
    const size_t oWendT = 0;                                   // 131,072,000
    const size_t oHidBf = oWendT + (size_t)V_DIM * H_DIM * 2;  // 16,777,216
    const size_t oBias2 = oHidBf + (size_t)B_DIM * H_DIM * 2;  // 32,768
    const size_t oLse   = oBias2 + 4 * H_DIM * 4;              // 16,384
    const size_t oAin   = oLse + B_DIM * 4;                    // 33,554,432
    const size_t oWeT   = oAin + (size_t)B_DIM * DIN * 2;      // 16,777,216
    const size_t oA2    = oWeT + (size_t)E_DIM * DIN * 2;      // 33,554,432
    const size_t oWUT   = oA2  + (size_t)B_DIM * 4096 * 2;     // 67,108,864

    ushort* WendT = (ushort*)(ws + oWendT);
    ushort* hidBf = (ushort*)(ws + oHidBf);
    float*  bias2 = (float*)(ws + oBias2);
    float*  lse   = (float*)(ws + oLse);
    ushort* Ain   = (ushort*)(ws + oAin);
    ushort* WeT   = (ushort*)(ws + oWeT);
    ushort* A2    = (ushort*)(ws + oA2);
    ushort* WUT   = (ushort*)(ws + oWUT);

    float* out  = (float*)d_out;
    float* outH = out + (size_t)B_DIM * V_DIM;
    float* outC = outH + (size_t)B_DIM * H_DIM;

    dim3 blk256(256), blk512(512);

    // P0: convert input + hidden, transpose all weights, pack biases
    k_cvt<<<dim3((B_DIM * DIN / 4) / 256), blk256, 0, stream>>>(in_input, Ain, B_DIM * DIN / 4);
    k_cvt_hidden<<<dim3((B_DIM * H_DIM / 4) / 256), blk256, 0, stream>>>(in_hidden, A2);

    dim3 tb(32, 8);
    k_transpose_bf16<<<dim3(E_DIM / 32, DIN / 32), tb, 0, stream>>>(We, WeT, E_DIM, DIN, 0, 0);
    k_transpose_gate<<<dim3(H_DIM / 32, E_DIM / 32), tb, 0, stream>>>(Wf, WUT, 0, 0);
    k_transpose_gate<<<dim3(H_DIM / 32, E_DIM / 32), tb, 0, stream>>>(Wi, WUT, 1, 0);
    k_transpose_gate<<<dim3(H_DIM / 32, E_DIM / 32), tb, 0, stream>>>(Wc, WUT, 2, 0);
    k_transpose_gate<<<dim3(H_DIM / 32, E_DIM / 32), tb, 0, stream>>>(Wo, WUT, 3, 0);
    k_transpose_gate<<<dim3(H_DIM / 32, H_DIM / 32), tb, 0, stream>>>(Uf, WUT, 0, 2048);
    k_transpose_gate<<<dim3(H_DIM / 32, H_DIM / 32), tb, 0, stream>>>(Ui, WUT, 1, 2048);
    k_transpose_gate<<<dim3(H_DIM / 32, H_DIM / 32), tb, 0, stream>>>(Uc, WUT, 2, 2048);
    k_transpose_gate<<<dim3(H_DIM / 32, H_DIM / 32), tb, 0, stream>>>(Uo, WUT, 3, 2048);
    k_transpose_bf16<<<dim3(V_DIM / 32, H_DIM / 32), tb, 0, stream>>>(Wend, WendT, V_DIM, H_DIM, 0, 0);
    k_biaspack<<<dim3(H_DIM / 256), blk256, 0, stream>>>(bfv, bhf, biv, bhi, bcv, bhc, bov, bho, bias2);

    // P1: emb = input @ We + be -> A2 left half (bf16)  [128^2 kernel: 512 blocks]
    k_gemm_bt<1><<<dim3((B_DIM / 128) * (E_DIM / 128)), blk256, 0, stream>>>(
        Ain, WeT, A2, be, B_DIM, E_DIM, DIN, DIN, DIN, 4096);

    // P2: gates GEMM + fused LSTM cell -> outH/outC/hidBf  [256^2 8-phase]
    k_gemm256<2><<<dim3((B_DIM / 256) * (8192 / 256)), blk512, 0, stream>>>(
        A2, WUT, nullptr, bias2, 8192, 4096, 4096, 4096, 0,
        in_cell, outH, outC, hidBf);

    // P3: logits = new_hidden @ Wend + bend -> d_out (fp32)  [256^2 8-phase]
    k_gemm256<0><<<dim3((B_DIM / 256) * (V_DIM / 256)), blk512, 0, stream>>>(
        hidBf, WendT, out, bend, V_DIM, H_DIM, H_DIM, H_DIM, V_DIM,
        nullptr, nullptr, nullptr, nullptr);

    // P4: log_softmax
    k_rowstats<<<dim3(B_DIM), blk256, 0, stream>>>(out, lse);
    k_norm<<<dim3(B_DIM * (V_DIM / 4) / 256), blk256, 0, stream>>>(out, lse);
}

// Round 4
// 1455.822 us; speedup vs baseline: 1.1489x; 1.1180x over previous
//
#include <hip/hip_runtime.h>
#include <stdint.h>

#define B_DIM 4096
#define DIN   4096
#define E_DIM 2048
#define H_DIM 2048
#define V_DIM 32000

typedef __attribute__((ext_vector_type(8))) short s8v;     // 8 x bf16 (MFMA A/B frag)
typedef __attribute__((ext_vector_type(4))) float f4v;     // MFMA C/D frag

__device__ __forceinline__ ushort f2bf(float f) {
    union { float f; uint32_t u; } v; v.f = f;
    uint32_t u = v.u;
    return (ushort)((u + 0x7FFFu + ((u >> 16) & 1u)) >> 16);
}

// ---------------- fp32 -> bf16 plain convert ----------------
__global__ void k_cvt(const float* __restrict__ src, ushort* __restrict__ dst, int n4) {
    int i = blockIdx.x * blockDim.x + threadIdx.x;
    if (i >= n4) return;
    float4 v = *(const float4*)(src + (size_t)i * 4);
    ushort4 o;
    o.x = f2bf(v.x); o.y = f2bf(v.y); o.z = f2bf(v.z); o.w = f2bf(v.w);
    *(ushort4*)(dst + (size_t)i * 4) = o;
}

// hidden [4096][2048] fp32 -> A2 right half (row stride 4096, col offset 2048)
__global__ void k_cvt_hidden(const float* __restrict__ src, ushort* __restrict__ dst) {
    int i = blockIdx.x * blockDim.x + threadIdx.x;
    int b = i >> 9;
    int c = (i & 511) << 2;
    float4 v = *(const float4*)(src + (size_t)b * H_DIM + c);
    ushort4 o;
    o.x = f2bf(v.x); o.y = f2bf(v.y); o.z = f2bf(v.z); o.w = f2bf(v.w);
    *(ushort4*)(dst + (size_t)b * 4096 + 2048 + c) = o;
}

// ---------------- transpose + convert: src fp32 [K x N] -> dst bf16 [N x K] ----------------
__global__ void k_transpose_bf16(const float* __restrict__ src, ushort* __restrict__ dst,
                                 int srcCols, int dstStride, int dstRowOff, int dstColOff) {
    __shared__ float tile[32][33];
    int tx = threadIdx.x, ty = threadIdx.y;
    int n0 = blockIdx.x * 32, k0 = blockIdx.y * 32;
#pragma unroll
    for (int i = 0; i < 4; i++)
        tile[ty + 8 * i][tx] = src[(size_t)(k0 + ty + 8 * i) * srcCols + n0 + tx];
    __syncthreads();
#pragma unroll
    for (int i = 0; i < 4; i++) {
        int n = ty + 8 * i;
        dst[(size_t)(dstRowOff + n0 + n) * dstStride + dstColOff + k0 + tx] = f2bf(tile[tx][n]);
    }
}

// gate-interleaved transpose for the 256^2 col mapping:
// packed col(g,h) = (h>>6)*256 + (g>>1)*128 + ((h>>4)&3)*32 + (g&1)*16 + (h&15)
__global__ void k_transpose_gate(const float* __restrict__ src, ushort* __restrict__ dst,
                                 int g, int dstColOff) {
    __shared__ float tile[32][33];
    int tx = threadIdx.x, ty = threadIdx.y;
    int n0 = blockIdx.x * 32, k0 = blockIdx.y * 32;
#pragma unroll
    for (int i = 0; i < 4; i++)
        tile[ty + 8 * i][tx] = src[(size_t)(k0 + ty + 8 * i) * H_DIM + n0 + tx];
    __syncthreads();
#pragma unroll
    for (int i = 0; i < 4; i++) {
        int h = n0 + ty + 8 * i;
        int drow = ((h >> 6) << 8) + ((g >> 1) << 7) + (((h >> 4) & 3) << 5) + ((g & 1) << 4) + (h & 15);
        dst[(size_t)drow * 4096 + dstColOff + k0 + tx] = f2bf(tile[tx][ty + 8 * i]);
    }
}

__global__ void k_biaspack(const float* __restrict__ b0, const float* __restrict__ bh0,
                           const float* __restrict__ b1, const float* __restrict__ bh1,
                           const float* __restrict__ b2, const float* __restrict__ bh2,
                           const float* __restrict__ b3, const float* __restrict__ bh3,
                           float* __restrict__ out) {
    int h = blockIdx.x * blockDim.x + threadIdx.x;
    if (h >= H_DIM) return;
    int base = ((h >> 6) << 8) + (((h >> 4) & 3) << 5) + (h & 15);
    out[base]             = b0[h] + bh0[h];   // g=0: f
    out[base + 16]        = b1[h] + bh1[h];   // g=1: i
    out[base + 128]       = b2[h] + bh2[h];   // g=2: c
    out[base + 128 + 16]  = b3[h] + bh3[h];   // g=3: o
}

// ---------------- 128x128 2-phase GEMM (emb only: grid 512 fills GPU) ----------------
template<int OUT_BF16>
__global__ __launch_bounds__(256, 2)
void k_gemm_bt(const ushort* __restrict__ A, const ushort* __restrict__ Bt,
               void* __restrict__ Cv, const float* __restrict__ bias,
               int M, int N, int K, int lda, int ldb, int ldc) {
    __shared__ __align__(16) ushort ldsA[128 * 64];
    __shared__ __align__(16) ushort ldsB[128 * 64];
    const int t = threadIdx.x;
    const int wid = t >> 6, lane = t & 63;

    int nwg = gridDim.x;
    int bid = blockIdx.x;
    int wg  = (bid & 7) * (nwg >> 3) + (bid >> 3);
    int NT  = N >> 7;
    int mt  = wg / NT, nt = wg - mt * NT;
    int m0  = mt << 7, n0 = nt << 7;

    f4v acc[4][4];
#pragma unroll
    for (int i = 0; i < 4; i++)
#pragma unroll
        for (int j = 0; j < 4; j++) acc[i][j] = (f4v){0.f, 0.f, 0.f, 0.f};

    const int wr = wid >> 1, wc = wid & 1;

    const int kTiles = K >> 6;
    for (int kt = 0; kt < kTiles; ++kt) {
#pragma unroll
        for (int c = 0; c < 4; ++c) {
            int idx = c * 256 + wid * 64 + lane;
            int row = idx >> 3;
            int kb  = (idx & 7) << 4;
            const ushort* gA = A  + (size_t)(m0 + row) * lda + (kt << 6) + (kb >> 1);
            const ushort* gB = Bt + (size_t)(n0 + row) * ldb + (kt << 6) + (kb >> 1);
            char* lA = (char*)ldsA + (size_t)(c * 256 + wid * 64) * 16;
            char* lB = (char*)ldsB + (size_t)(c * 256 + wid * 64) * 16;
            __builtin_amdgcn_global_load_lds((const __attribute__((address_space(1))) void*)gA,
                                             (__attribute__((address_space(3))) void*)lA, 16, 0, 0);
            __builtin_amdgcn_global_load_lds((const __attribute__((address_space(1))) void*)gB,
                                             (__attribute__((address_space(3))) void*)lB, 16, 0, 0);
        }
        __syncthreads();

#pragma unroll
        for (int ks = 0; ks < 2; ++ks) {
            s8v af[4], bfr[4];
#pragma unroll
            for (int m = 0; m < 4; ++m) {
                int r = wr * 64 + m * 16 + (lane & 15);
                int kb = ks * 64 + ((lane >> 4) << 4);
                af[m] = *(const s8v*)((const char*)ldsA + r * 128 + kb);
            }
#pragma unroll
            for (int n = 0; n < 4; ++n) {
                int r = wc * 64 + n * 16 + (lane & 15);
                int kb = ks * 64 + ((lane >> 4) << 4);
                bfr[n] = *(const s8v*)((const char*)ldsB + r * 128 + kb);
            }
#pragma unroll
            for (int m = 0; m < 4; ++m)
#pragma unroll
                for (int n = 0; n < 4; ++n)
                    acc[m][n] = __builtin_amdgcn_mfma_f32_16x16x32_bf16(af[m], bfr[n], acc[m][n], 0, 0, 0);
        }
        __syncthreads();
    }

#pragma unroll
    for (int n = 0; n < 4; ++n) {
        int cg = n0 + wc * 64 + n * 16 + (lane & 15);
        float bv = bias[cg];
#pragma unroll
        for (int m = 0; m < 4; ++m) {
            int rbase = m0 + wr * 64 + m * 16 + ((lane >> 4) << 2);
#pragma unroll
            for (int r = 0; r < 4; ++r) {
                float v = acc[m][n][r] + bv;
                if (OUT_BF16)
                    ((ushort*)Cv)[(size_t)(rbase + r) * ldc + cg] = f2bf(v);
                else
                    ((float*)Cv)[(size_t)(rbase + r) * ldc + cg] = v;
            }
        }
    }
}

// ---------------- 256x256 8-phase GEMM (m201 discipline), BK=64, 8 waves ----------------
// Phase p consumes half X; half X is restaged no earlier than phase p+1 (race-free:
// all waves' ds_reads of X complete before the closing barrier of phase p).
// Stage slots: ph1=A0, ph2=B0, ph3=B1+A1. vmcnt(8) only at tile boundary.
// EPI 0 = fp32+bias + fused row max/sumexp partials; EPI 2 = fused LSTM cell.
template<int EPI>
__global__ __launch_bounds__(512, 2)
void k_gemm256(const ushort* __restrict__ A, const ushort* __restrict__ Bt,
               void* __restrict__ Cv, const float* __restrict__ bias,
               int N, int K, int lda, int ldb, int ldc,
               const float* __restrict__ cell, float* __restrict__ outH,
               float* __restrict__ outC, ushort* __restrict__ hidBf,
               float2* __restrict__ partials, int ncb) {
    __shared__ __align__(16) ushort ldsA[2][256 * 64];   // 64 KB
    __shared__ __align__(16) ushort ldsB[2][256 * 64];   // 64 KB
    const int t = threadIdx.x;
    const int wid = t >> 6, lane = t & 63;
    const int wr = wid >> 2, wc = wid & 3;

    int nwg = gridDim.x, bid = blockIdx.x;
    int wg = (bid & 7) * (nwg >> 3) + (bid >> 3);
    int NT = N >> 8;
    int mt = wg / NT, nt = wg - mt * NT;
    int m0 = mt << 8, n0 = nt << 8;

    // staging geometry: idx = cc*512 + t -> row = idx>>3 (cc 0..1: half0, 2..3: half1)
    // source pre-swizzled: chunk = (idx&7) ^ (row&7); LDS dest linear.
    int offA[4], offB[4];
#pragma unroll
    for (int cc = 0; cc < 4; ++cc) {
        int idx = cc * 512 + t;
        int row = idx >> 3;
        int col = ((idx & 7) ^ (row & 7)) << 3;
        offA[cc] = (m0 + row) * lda + col;
        offB[cc] = (n0 + row) * ldb + col;
    }

#define GLOAD(GP, LP) __builtin_amdgcn_global_load_lds(                                   \
        (const __attribute__((address_space(1))) void*)(GP),                              \
        (__attribute__((address_space(3))) void*)(LP), 16, 0, 0)
#define STAGE_HA(BUF, KT, H) do {                                                         \
    GLOAD(A + offA[(H)*2]     + ((KT) << 6), &ldsA[BUF][(((H)*2)*512 + (wid<<6)) * 8]);   \
    GLOAD(A + offA[(H)*2 + 1] + ((KT) << 6), &ldsA[BUF][(((H)*2+1)*512 + (wid<<6)) * 8]); \
} while (0)
#define STAGE_HB(BUF, KT, H) do {                                                         \
    GLOAD(Bt + offB[(H)*2]     + ((KT) << 6), &ldsB[BUF][(((H)*2)*512 + (wid<<6)) * 8]);  \
    GLOAD(Bt + offB[(H)*2 + 1] + ((KT) << 6), &ldsB[BUF][(((H)*2+1)*512 + (wid<<6)) * 8]);\
} while (0)

    f4v acc[8][4];
#pragma unroll
    for (int i = 0; i < 8; i++)
#pragma unroll
        for (int j = 0; j < 4; j++) acc[i][j] = (f4v){0.f, 0.f, 0.f, 0.f};

    s8v af[4][2], bfA[2][2], bfB[2][2];
    const int swz = (lane & 7) << 4;
    const int kcol = (lane >> 4) << 4;

#define READ_A(BUF, MH) do {                                                              \
    _Pragma("unroll")                                                                     \
    for (int m_ = 0; m_ < 4; ++m_) {                                                      \
        int row = (MH)*128 + wr*64 + m_*16 + (lane & 15);                                 \
        _Pragma("unroll")                                                                 \
        for (int ks_ = 0; ks_ < 2; ++ks_)                                                 \
            af[m_][ks_] = *(const s8v*)((const char*)&ldsA[BUF][0] + row * 128 +          \
                                        ((ks_*64 + kcol) ^ swz));                         \
    } } while (0)
#define READ_B(BUF, NH, DST) do {                                                         \
    _Pragma("unroll")                                                                     \
    for (int n_ = 0; n_ < 2; ++n_) {                                                      \
        int row = (NH)*128 + wc*32 + n_*16 + (lane & 15);                                 \
        _Pragma("unroll")                                                                 \
        for (int ks_ = 0; ks_ < 2; ++ks_)                                                 \
            DST[n_][ks_] = *(const s8v*)((const char*)&ldsB[BUF][0] + row * 128 +         \
                                         ((ks_*64 + kcol) ^ swz));                        \
    } } while (0)
#define MFMA_Q(MH, NH, BF) do {                                                           \
    __builtin_amdgcn_s_setprio(1);                                                        \
    _Pragma("unroll")                                                                     \
    for (int m_ = 0; m_ < 4; ++m_)                                                        \
    _Pragma("unroll")                                                                     \
    for (int n_ = 0; n_ < 2; ++n_)                                                        \
    _Pragma("unroll")                                                                     \
    for (int ks_ = 0; ks_ < 2; ++ks_)                                                     \
        acc[(MH)*4 + m_][(NH)*2 + n_] = __builtin_amdgcn_mfma_f32_16x16x32_bf16(          \
            af[m_][ks_], BF[n_][ks_], acc[(MH)*4 + m_][(NH)*2 + n_], 0, 0, 0);            \
    __builtin_amdgcn_s_setprio(0);                                                        \
} while (0)
#define MEMBAR asm volatile("" ::: "memory")
#define BAR() do { MEMBAR; __builtin_amdgcn_s_barrier(); MEMBAR; } while (0)
#define WAITLGKM0() do { asm volatile("s_waitcnt lgkmcnt(0)" ::: "memory");               \
                         __builtin_amdgcn_sched_barrier(0); } while (0)

    const int kTiles = K >> 6;
    // prologue: tile0 {A0,B0,B1,A1}, tile1 {A0,B0,B1,A1} -> 16 loads in flight
    STAGE_HA(0, 0, 0); STAGE_HB(0, 0, 0); STAGE_HB(0, 0, 1); STAGE_HA(0, 0, 1);
    STAGE_HA(1, 1, 0); STAGE_HB(1, 1, 0); STAGE_HB(1, 1, 1); STAGE_HA(1, 1, 1);
    asm volatile("s_waitcnt vmcnt(6)" ::: "memory");   // tile0 fully landed
    BAR();

    for (int kt = 0; kt < kTiles; ++kt) {
        const int buf = kt & 1;
        const bool pf = (kt + 2 < kTiles);
        // ---- ph0: quadrant (0,0); NO restage (A0/B0 being read right now) ----
        READ_A(buf, 0); READ_B(buf, 0, bfA);
        asm volatile("s_waitcnt lgkmcnt(8)" ::: "memory");
        BAR(); WAITLGKM0();
        MFMA_Q(0, 0, bfA);
        BAR();
        // ---- ph1: quadrant (0,1); restage A0 (reads done in ph0) ----
        READ_B(buf, 1, bfB);
        if (pf) STAGE_HA(buf, kt + 2, 0);
        BAR(); WAITLGKM0();
        MFMA_Q(0, 1, bfB);
        BAR();
        // ---- ph2: quadrant (1,1); restage B0 (reads done in ph0) ----
        READ_A(buf, 1);
        if (pf) STAGE_HB(buf, kt + 2, 0);
        BAR(); WAITLGKM0();
        MFMA_Q(1, 1, bfB);
        BAR();
        // ---- ph3: quadrant (1,0); restage B1+A1 (reads done in ph1/ph2); boundary sync ----
        if (pf) { STAGE_HB(buf, kt + 2, 1); STAGE_HA(buf, kt + 2, 1); }
        MFMA_Q(1, 0, bfA);
        if (pf) asm volatile("s_waitcnt vmcnt(8)" ::: "memory");
        else    asm volatile("s_waitcnt vmcnt(0)" ::: "memory");
        BAR();
    }

    // ---------------- epilogue ----------------
    if (EPI == 0) {
        float bv[4];
#pragma unroll
        for (int j = 0; j < 4; ++j)
            bv[j] = bias[n0 + (j >> 1) * 128 + wc * 32 + (j & 1) * 16 + (lane & 15)];
        float2* sm = (float2*)&ldsA[0][0];    // [4 wc][256 rows], loop LDS is dead
#pragma unroll
        for (int mh = 0; mh < 2; ++mh)
#pragma unroll
        for (int m = 0; m < 4; ++m) {
            int rl = mh * 128 + wr * 64 + m * 16 + ((lane >> 4) << 2);
            int rb = m0 + rl;
#pragma unroll
            for (int r = 0; r < 4; ++r) {
                float v[4];
#pragma unroll
                for (int j = 0; j < 4; ++j) {
                    v[j] = acc[mh * 4 + m][j][r] + bv[j];
                    int cg = n0 + (j >> 1) * 128 + wc * 32 + (j & 1) * 16 + (lane & 15);
                    ((float*)Cv)[(size_t)(rb + r) * ldc + cg] = v[j];
                }
                float mx = fmaxf(fmaxf(v[0], v[1]), fmaxf(v[2], v[3]));
                float ss = __expf(v[0] - mx) + __expf(v[1] - mx) +
                           __expf(v[2] - mx) + __expf(v[3] - mx);
#pragma unroll
                for (int off = 1; off < 16; off <<= 1) {
                    float mo = __shfl_xor(mx, off);
                    float so = __shfl_xor(ss, off);
                    float nm = fmaxf(mx, mo);
                    ss = ss * __expf(mx - nm) + so * __expf(mo - nm);
                    mx = nm;
                }
                if ((lane & 15) == 0) sm[wc * 256 + rl + r] = make_float2(mx, ss);
            }
        }
        __syncthreads();
        if (t < 256) {
            float2 p = sm[t];
            float M = p.x, S = p.y;
#pragma unroll
            for (int w = 1; w < 4; ++w) {
                float2 q = sm[w * 256 + t];
                float nm = fmaxf(M, q.x);
                S = S * __expf(M - nm) + q.y * __expf(q.x - nm);
                M = nm;
            }
            partials[(size_t)(m0 + t) * ncb + (n0 >> 8)] = make_float2(M, S);
        }
    } else {
        // gate-fused: lane's 4 acc-cols are gates f,i,c,o of h = n0/4 + wc*16 + (lane&15)
        int h = (n0 >> 2) + wc * 16 + (lane & 15);
        float bv[4];
#pragma unroll
        for (int j = 0; j < 4; ++j)
            bv[j] = bias[n0 + (j >> 1) * 128 + wc * 32 + (j & 1) * 16 + (lane & 15)];
#pragma unroll
        for (int mh = 0; mh < 2; ++mh)
#pragma unroll
        for (int m = 0; m < 4; ++m) {
            int rb = m0 + mh * 128 + wr * 64 + m * 16 + ((lane >> 4) << 2);
#pragma unroll
            for (int r = 0; r < 4; ++r) {
                int b = rb + r;
                float pf_ = acc[mh * 4 + m][0][r] + bv[0];
                float pi_ = acc[mh * 4 + m][1][r] + bv[1];
                float pc_ = acc[mh * 4 + m][2][r] + bv[2];
                float po_ = acc[mh * 4 + m][3][r] + bv[3];
                float fg = 1.f / (1.f + __expf(-pf_));
                float ig = 1.f / (1.f + __expf(-pi_));
                float gg = tanhf(pc_);
                float og = 1.f / (1.f + __expf(-po_));
                size_t off = (size_t)b * H_DIM + h;
                float nc = fg * cell[off] + ig * gg;
                float nh = og * tanhf(nc);
                outC[off] = nc;
                outH[off] = nh;
                hidBf[off] = f2bf(nh);
            }
        }
    }
#undef GLOAD
#undef STAGE_HA
#undef STAGE_HB
#undef READ_A
#undef READ_B
#undef MFMA_Q
#undef MEMBAR
#undef BAR
#undef WAITLGKM0
}

// ---------------- reduce per-block (m,s) partials -> lse[row] ----------------
__global__ void k_lsefin(const float2* __restrict__ part, float* __restrict__ lse, int ncb) {
    int row = blockIdx.x;
    int l = threadIdx.x;   // 64
    float M = -1e30f, S = 0.f;
    for (int i = l; i < ncb; i += 64) {
        float2 p = part[(size_t)row * ncb + i];
        float nm = fmaxf(M, p.x);
        S = S * __expf(M - nm) + p.y * __expf(p.x - nm);
        M = nm;
    }
#pragma unroll
    for (int off = 1; off < 64; off <<= 1) {
        float Mo = __shfl_xor(M, off);
        float So = __shfl_xor(S, off);
        float nm = fmaxf(M, Mo);
        S = S * __expf(M - nm) + So * __expf(Mo - nm);
        M = nm;
    }
    if (l == 0) lse[row] = M + logf(S);
}

__global__ void k_norm(float* __restrict__ out, const float* __restrict__ lse) {
    int i = blockIdx.x * blockDim.x + threadIdx.x;
    int b = i / (V_DIM / 4);
    int c = (i - b * (V_DIM / 4)) * 4;
    float l = lse[b];
    float* p = out + (size_t)b * V_DIM + c;
    float4 v = *(const float4*)p;
    v.x -= l; v.y -= l; v.z -= l; v.w -= l;
    *(float4*)p = v;
}

extern "C" void kernel_launch(void* const* d_in, const int* in_sizes, int n_in,
                              void* d_out, int out_size, void* d_ws, size_t ws_size,
                              hipStream_t stream) {
    const float* in_input  = (const float*)d_in[0];
    const float* in_hidden = (const float*)d_in[1];
    const float* in_cell   = (const float*)d_in[2];
    const float* We   = (const float*)d_in[3];
    const float* be   = (const float*)d_in[4];
    const float* Wf   = (const float*)d_in[5];
    const float* bfv  = (const float*)d_in[6];
    const float* Wi   = (const float*)d_in[7];
    const float* biv  = (const float*)d_in[8];
    const float* Wc   = (const float*)d_in[9];
    const float* bcv  = (const float*)d_in[10];
    const float* Wo   = (const float*)d_in[11];
    const float* bov  = (const float*)d_in[12];
    const float* Uf   = (const float*)d_in[13];
    const float* bhf  = (const float*)d_in[14];
    const float* Ui   = (const float*)d_in[15];
    const float* bhi  = (const float*)d_in[16];
    const float* Uc   = (const float*)d_in[17];
    const float* bhc  = (const float*)d_in[18];
    const float* Uo   = (const float*)d_in[19];
    const float* bho  = (const float*)d_in[20];
    const float* Wend = (const float*)d_in[21];
    const float* bend = (const float*)d_in[22];

    char* ws = (char*)d_ws;
    const size_t oWendT = 0;                                   // 131,072,000
    const size_t oHidBf = oWendT + (size_t)V_DIM * H_DIM * 2;  // 16,777,216
    const size_t oBias2 = oHidBf + (size_t)B_DIM * H_DIM * 2;  // 32,768
    const size_t oLse   = oBias2 + 4 * H_DIM * 4;              // 16,384
    const size_t oPart  = oLse + B_DIM * 4;                    // 4096*125*8 = 4,096,000
    const size_t oAin   = oPart + (size_t)B_DIM * 125 * 8;     // 33,554,432
    const size_t oWeT   = oAin + (size_t)B_DIM * DIN * 2;      // 16,777,216
    const size_t oA2    = oWeT + (size_t)E_DIM * DIN * 2;      // 33,554,432
    const size_t oWUT   = oA2  + (size_t)B_DIM * 4096 * 2;     // 67,108,864

    ushort* WendT = (ushort*)(ws + oWendT);
    ushort* hidBf = (ushort*)(ws + oHidBf);
    float*  bias2 = (float*)(ws + oBias2);
    float*  lse   = (float*)(ws + oLse);
    float2* part  = (float2*)(ws + oPart);
    ushort* Ain   = (ushort*)(ws + oAin);
    ushort* WeT   = (ushort*)(ws + oWeT);
    ushort* A2    = (ushort*)(ws + oA2);
    ushort* WUT   = (ushort*)(ws + oWUT);

    float* out  = (float*)d_out;
    float* outH = out + (size_t)B_DIM * V_DIM;
    float* outC = outH + (size_t)B_DIM * H_DIM;

    const int NCB = V_DIM / 256;   // 125

    dim3 blk256(256), blk512(512), blk64(64);

    // P0: convert input + hidden, transpose all weights, pack biases
    k_cvt<<<dim3((B_DIM * DIN / 4) / 256), blk256, 0, stream>>>(in_input, Ain, B_DIM * DIN / 4);
    k_cvt_hidden<<<dim3((B_DIM * H_DIM / 4) / 256), blk256, 0, stream>>>(in_hidden, A2);

    dim3 tb(32, 8);
    k_transpose_bf16<<<dim3(E_DIM / 32, DIN / 32), tb, 0, stream>>>(We, WeT, E_DIM, DIN, 0, 0);
    k_transpose_gate<<<dim3(H_DIM / 32, E_DIM / 32), tb, 0, stream>>>(Wf, WUT, 0, 0);
    k_transpose_gate<<<dim3(H_DIM / 32, E_DIM / 32), tb, 0, stream>>>(Wi, WUT, 1, 0);
    k_transpose_gate<<<dim3(H_DIM / 32, E_DIM / 32), tb, 0, stream>>>(Wc, WUT, 2, 0);
    k_transpose_gate<<<dim3(H_DIM / 32, E_DIM / 32), tb, 0, stream>>>(Wo, WUT, 3, 0);
    k_transpose_gate<<<dim3(H_DIM / 32, H_DIM / 32), tb, 0, stream>>>(Uf, WUT, 0, 2048);
    k_transpose_gate<<<dim3(H_DIM / 32, H_DIM / 32), tb, 0, stream>>>(Ui, WUT, 1, 2048);
    k_transpose_gate<<<dim3(H_DIM / 32, H_DIM / 32), tb, 0, stream>>>(Uc, WUT, 2, 2048);
    k_transpose_gate<<<dim3(H_DIM / 32, H_DIM / 32), tb, 0, stream>>>(Uo, WUT, 3, 2048);
    k_transpose_bf16<<<dim3(V_DIM / 32, H_DIM / 32), tb, 0, stream>>>(Wend, WendT, V_DIM, H_DIM, 0, 0);
    k_biaspack<<<dim3(H_DIM / 256), blk256, 0, stream>>>(bfv, bhf, biv, bhi, bcv, bhc, bov, bho, bias2);

    // P1: emb = input @ We + be -> A2 left half (bf16)
    k_gemm_bt<1><<<dim3((B_DIM / 128) * (E_DIM / 128)), blk256, 0, stream>>>(
        Ain, WeT, A2, be, B_DIM, E_DIM, DIN, DIN, DIN, 4096);

    // P2: gates GEMM + fused LSTM cell -> outH/outC/hidBf
    k_gemm256<2><<<dim3((B_DIM / 256) * (8192 / 256)), blk512, 0, stream>>>(
        A2, WUT, nullptr, bias2, 8192, 4096, 4096, 4096, 0,
        in_cell, outH, outC, hidBf, nullptr, 0);

    // P3: logits = new_hidden @ Wend + bend -> d_out (fp32), fused row-stat partials
    k_gemm256<0><<<dim3((B_DIM / 256) * (V_DIM / 256)), blk512, 0, stream>>>(
        hidBf, WendT, out, bend, V_DIM, H_DIM, H_DIM, H_DIM, V_DIM,
        nullptr, nullptr, nullptr, nullptr, part, NCB);

    // P4: finish log_softmax
    k_lsefin<<<dim3(B_DIM), blk64, 0, stream>>>(part, lse, NCB);
    k_norm<<<dim3(B_DIM * (V_DIM / 4) / 256), blk256, 0, stream>>>(out, lse);
}

// Round 5
// 1218.965 us; speedup vs baseline: 1.3722x; 1.1943x over previous
//
#include <hip/hip_runtime.h>
#include <stdint.h>

#define B_DIM 4096
#define DIN   4096
#define E_DIM 2048
#define H_DIM 2048
#define V_DIM 32000

typedef __attribute__((ext_vector_type(8))) short s8v;     // 8 x bf16 (MFMA A/B frag)
typedef __attribute__((ext_vector_type(4))) float f4v;     // MFMA C/D frag
typedef __attribute__((ext_vector_type(4))) int   i4v;
typedef __attribute__((ext_vector_type(8))) int   i8v;     // fp8 MFMA A/B operand (32 B)
typedef __attribute__((ext_vector_type(16))) float f16v;   // 32x32 MFMA C/D

__device__ __forceinline__ ushort f2bf(float f) {
    union { float f; uint32_t u; } v; v.f = f;
    uint32_t u = v.u;
    return (ushort)((u + 0x7FFFu + ((u >> 16) & 1u)) >> 16);
}

// float -> OCP e4m3fn, RNE (values expected pre-scaled into normal range)
__device__ __forceinline__ uint8_t f2fp8(float x) {
    union { float f; uint32_t u; } v; v.f = x;
    uint8_t sign = (uint8_t)((v.u >> 24) & 0x80u);
    uint32_t a = v.u & 0x7FFFFFFFu;
    if (a >= 0x43E00000u) return sign | 0x7E;            // >= 448 -> clamp
    uint32_t r = a + 0x0007FFFFu + ((a >> 20) & 1u);     // RNE at bit 20
    int e = (int)(r >> 23) - 127 + 7;
    if (e <= 0) {                                         // subnormal: multiples of 2^-9
        float s = fabsf(x);
        int q = (int)(s * 512.0f + 0.5f);
        if (q > 7) q = 7;
        return sign | (uint8_t)q;
    }
    uint32_t m = (r >> 20) & 7u;
    uint8_t b = (uint8_t)((e << 3) | m);
    if (b == 0x7F) b = 0x7E;                              // avoid NaN encoding
    return sign | b;
}

// ---------------- fp32 -> bf16 plain convert ----------------
__global__ void k_cvt(const float* __restrict__ src, ushort* __restrict__ dst, int n4) {
    int i = blockIdx.x * blockDim.x + threadIdx.x;
    if (i >= n4) return;
    float4 v = *(const float4*)(src + (size_t)i * 4);
    ushort4 o;
    o.x = f2bf(v.x); o.y = f2bf(v.y); o.z = f2bf(v.z); o.w = f2bf(v.w);
    *(ushort4*)(dst + (size_t)i * 4) = o;
}

// hidden [4096][2048] fp32 -> A2 right half (row stride 4096, col offset 2048)
__global__ void k_cvt_hidden(const float* __restrict__ src, ushort* __restrict__ dst) {
    int i = blockIdx.x * blockDim.x + threadIdx.x;
    int b = i >> 9;
    int c = (i & 511) << 2;
    float4 v = *(const float4*)(src + (size_t)b * H_DIM + c);
    ushort4 o;
    o.x = f2bf(v.x); o.y = f2bf(v.y); o.z = f2bf(v.z); o.w = f2bf(v.w);
    *(ushort4*)(dst + (size_t)b * 4096 + 2048 + c) = o;
}

// ---------------- transpose + convert: src fp32 [K x N] -> dst bf16 [N x K] ----------------
__global__ void k_transpose_bf16(const float* __restrict__ src, ushort* __restrict__ dst,
                                 int srcCols, int dstStride, int dstRowOff, int dstColOff) {
    __shared__ float tile[32][33];
    int tx = threadIdx.x, ty = threadIdx.y;
    int n0 = blockIdx.x * 32, k0 = blockIdx.y * 32;
#pragma unroll
    for (int i = 0; i < 4; i++)
        tile[ty + 8 * i][tx] = src[(size_t)(k0 + ty + 8 * i) * srcCols + n0 + tx];
    __syncthreads();
#pragma unroll
    for (int i = 0; i < 4; i++) {
        int n = ty + 8 * i;
        dst[(size_t)(dstRowOff + n0 + n) * dstStride + dstColOff + k0 + tx] = f2bf(tile[tx][n]);
    }
}

// transpose + convert + scale: src fp32 [K x N] -> dst fp8 [N x K], val*32 (scale 2^-5 in MFMA)
__global__ void k_transpose_fp8(const float* __restrict__ src, uint8_t* __restrict__ dst,
                                int srcCols, int dstStride) {
    __shared__ float tile[32][33];
    int tx = threadIdx.x, ty = threadIdx.y;
    int n0 = blockIdx.x * 32, k0 = blockIdx.y * 32;
#pragma unroll
    for (int i = 0; i < 4; i++)
        tile[ty + 8 * i][tx] = src[(size_t)(k0 + ty + 8 * i) * srcCols + n0 + tx];
    __syncthreads();
#pragma unroll
    for (int i = 0; i < 4; i++) {
        int n = ty + 8 * i;
        dst[(size_t)(n0 + n) * dstStride + k0 + tx] = f2fp8(tile[tx][n] * 32.0f);
    }
}

// gate-interleaved transpose for the 256^2 col mapping:
// packed col(g,h) = (h>>6)*256 + (g>>1)*128 + ((h>>4)&3)*32 + (g&1)*16 + (h&15)
__global__ void k_transpose_gate(const float* __restrict__ src, ushort* __restrict__ dst,
                                 int g, int dstColOff) {
    __shared__ float tile[32][33];
    int tx = threadIdx.x, ty = threadIdx.y;
    int n0 = blockIdx.x * 32, k0 = blockIdx.y * 32;
#pragma unroll
    for (int i = 0; i < 4; i++)
        tile[ty + 8 * i][tx] = src[(size_t)(k0 + ty + 8 * i) * H_DIM + n0 + tx];
    __syncthreads();
#pragma unroll
    for (int i = 0; i < 4; i++) {
        int h = n0 + ty + 8 * i;
        int drow = ((h >> 6) << 8) + ((g >> 1) << 7) + (((h >> 4) & 3) << 5) + ((g & 1) << 4) + (h & 15);
        dst[(size_t)drow * 4096 + dstColOff + k0 + tx] = f2bf(tile[tx][ty + 8 * i]);
    }
}

__global__ void k_biaspack(const float* __restrict__ b0, const float* __restrict__ bh0,
                           const float* __restrict__ b1, const float* __restrict__ bh1,
                           const float* __restrict__ b2, const float* __restrict__ bh2,
                           const float* __restrict__ b3, const float* __restrict__ bh3,
                           float* __restrict__ out) {
    int h = blockIdx.x * blockDim.x + threadIdx.x;
    if (h >= H_DIM) return;
    int base = ((h >> 6) << 8) + (((h >> 4) & 3) << 5) + (h & 15);
    out[base]             = b0[h] + bh0[h];   // g=0: f
    out[base + 16]        = b1[h] + bh1[h];   // g=1: i
    out[base + 128]       = b2[h] + bh2[h];   // g=2: c
    out[base + 128 + 16]  = b3[h] + bh3[h];   // g=3: o
}

// ---------------- 128x128 2-phase bf16 GEMM (emb only) ----------------
template<int OUT_BF16>
__global__ __launch_bounds__(256, 2)
void k_gemm_bt(const ushort* __restrict__ A, const ushort* __restrict__ Bt,
               void* __restrict__ Cv, const float* __restrict__ bias,
               int M, int N, int K, int lda, int ldb, int ldc) {
    __shared__ __align__(16) ushort ldsA[128 * 64];
    __shared__ __align__(16) ushort ldsB[128 * 64];
    const int t = threadIdx.x;
    const int wid = t >> 6, lane = t & 63;

    int nwg = gridDim.x;
    int bid = blockIdx.x;
    int wg  = (bid & 7) * (nwg >> 3) + (bid >> 3);
    int NT  = N >> 7;
    int mt  = wg / NT, nt = wg - mt * NT;
    int m0  = mt << 7, n0 = nt << 7;

    f4v acc[4][4];
#pragma unroll
    for (int i = 0; i < 4; i++)
#pragma unroll
        for (int j = 0; j < 4; j++) acc[i][j] = (f4v){0.f, 0.f, 0.f, 0.f};

    const int wr = wid >> 1, wc = wid & 1;

    const int kTiles = K >> 6;
    for (int kt = 0; kt < kTiles; ++kt) {
#pragma unroll
        for (int c = 0; c < 4; ++c) {
            int idx = c * 256 + wid * 64 + lane;
            int row = idx >> 3;
            int kb  = (idx & 7) << 4;
            const ushort* gA = A  + (size_t)(m0 + row) * lda + (kt << 6) + (kb >> 1);
            const ushort* gB = Bt + (size_t)(n0 + row) * ldb + (kt << 6) + (kb >> 1);
            char* lA = (char*)ldsA + (size_t)(c * 256 + wid * 64) * 16;
            char* lB = (char*)ldsB + (size_t)(c * 256 + wid * 64) * 16;
            __builtin_amdgcn_global_load_lds((const __attribute__((address_space(1))) void*)gA,
                                             (__attribute__((address_space(3))) void*)lA, 16, 0, 0);
            __builtin_amdgcn_global_load_lds((const __attribute__((address_space(1))) void*)gB,
                                             (__attribute__((address_space(3))) void*)lB, 16, 0, 0);
        }
        __syncthreads();

#pragma unroll
        for (int ks = 0; ks < 2; ++ks) {
            s8v af[4], bfr[4];
#pragma unroll
            for (int m = 0; m < 4; ++m) {
                int r = wr * 64 + m * 16 + (lane & 15);
                int kb = ks * 64 + ((lane >> 4) << 4);
                af[m] = *(const s8v*)((const char*)ldsA + r * 128 + kb);
            }
#pragma unroll
            for (int n = 0; n < 4; ++n) {
                int r = wc * 64 + n * 16 + (lane & 15);
                int kb = ks * 64 + ((lane >> 4) << 4);
                bfr[n] = *(const s8v*)((const char*)ldsB + r * 128 + kb);
            }
#pragma unroll
            for (int m = 0; m < 4; ++m)
#pragma unroll
                for (int n = 0; n < 4; ++n)
                    acc[m][n] = __builtin_amdgcn_mfma_f32_16x16x32_bf16(af[m], bfr[n], acc[m][n], 0, 0, 0);
        }
        __syncthreads();
    }

#pragma unroll
    for (int n = 0; n < 4; ++n) {
        int cg = n0 + wc * 64 + n * 16 + (lane & 15);
        float bv = bias[cg];
#pragma unroll
        for (int m = 0; m < 4; ++m) {
            int rbase = m0 + wr * 64 + m * 16 + ((lane >> 4) << 2);
#pragma unroll
            for (int r = 0; r < 4; ++r) {
                float v = acc[m][n][r] + bv;
                if (OUT_BF16)
                    ((ushort*)Cv)[(size_t)(rbase + r) * ldc + cg] = f2bf(v);
                else
                    ((float*)Cv)[(size_t)(rbase + r) * ldc + cg] = v;
            }
        }
    }
}

// ---------------- 256x256 8-phase bf16 GEMM (gates, fused LSTM cell epilogue) ----------------
template<int EPI>
__global__ __launch_bounds__(512, 2)
void k_gemm256(const ushort* __restrict__ A, const ushort* __restrict__ Bt,
               void* __restrict__ Cv, const float* __restrict__ bias,
               int N, int K, int lda, int ldb, int ldc,
               const float* __restrict__ cell, float* __restrict__ outH,
               float* __restrict__ outC, uint8_t* __restrict__ hidF8,
               float2* __restrict__ partials, int ncb) {
    __shared__ __align__(16) ushort ldsA[2][256 * 64];   // 64 KB
    __shared__ __align__(16) ushort ldsB[2][256 * 64];   // 64 KB
    const int t = threadIdx.x;
    const int wid = t >> 6, lane = t & 63;
    const int wr = wid >> 2, wc = wid & 3;

    int nwg = gridDim.x, bid = blockIdx.x;
    int wg = (bid & 7) * (nwg >> 3) + (bid >> 3);
    int NT = N >> 8;
    int mt = wg / NT, nt = wg - mt * NT;
    int m0 = mt << 8, n0 = nt << 8;

    int offA[4], offB[4];
#pragma unroll
    for (int cc = 0; cc < 4; ++cc) {
        int idx = cc * 512 + t;
        int row = idx >> 3;
        int col = ((idx & 7) ^ (row & 7)) << 3;
        offA[cc] = (m0 + row) * lda + col;
        offB[cc] = (n0 + row) * ldb + col;
    }

#define GLOAD(GP, LP) __builtin_amdgcn_global_load_lds(                                   \
        (const __attribute__((address_space(1))) void*)(GP),                              \
        (__attribute__((address_space(3))) void*)(LP), 16, 0, 0)
#define STAGE_HA(BUF, KT, H) do {                                                         \
    GLOAD(A + offA[(H)*2]     + ((KT) << 6), &ldsA[BUF][(((H)*2)*512 + (wid<<6)) * 8]);   \
    GLOAD(A + offA[(H)*2 + 1] + ((KT) << 6), &ldsA[BUF][(((H)*2+1)*512 + (wid<<6)) * 8]); \
} while (0)
#define STAGE_HB(BUF, KT, H) do {                                                         \
    GLOAD(Bt + offB[(H)*2]     + ((KT) << 6), &ldsB[BUF][(((H)*2)*512 + (wid<<6)) * 8]);  \
    GLOAD(Bt + offB[(H)*2 + 1] + ((KT) << 6), &ldsB[BUF][(((H)*2+1)*512 + (wid<<6)) * 8]);\
} while (0)

    f4v acc[8][4];
#pragma unroll
    for (int i = 0; i < 8; i++)
#pragma unroll
        for (int j = 0; j < 4; j++) acc[i][j] = (f4v){0.f, 0.f, 0.f, 0.f};

    s8v af[4][2], bfA[2][2], bfB[2][2];
    const int swz = (lane & 7) << 4;
    const int kcol = (lane >> 4) << 4;

#define READ_A(BUF, MH) do {                                                              \
    _Pragma("unroll")                                                                     \
    for (int m_ = 0; m_ < 4; ++m_) {                                                      \
        int row = (MH)*128 + wr*64 + m_*16 + (lane & 15);                                 \
        _Pragma("unroll")                                                                 \
        for (int ks_ = 0; ks_ < 2; ++ks_)                                                 \
            af[m_][ks_] = *(const s8v*)((const char*)&ldsA[BUF][0] + row * 128 +          \
                                        ((ks_*64 + kcol) ^ swz));                         \
    } } while (0)
#define READ_B(BUF, NH, DST) do {                                                         \
    _Pragma("unroll")                                                                     \
    for (int n_ = 0; n_ < 2; ++n_) {                                                      \
        int row = (NH)*128 + wc*32 + n_*16 + (lane & 15);                                 \
        _Pragma("unroll")                                                                 \
        for (int ks_ = 0; ks_ < 2; ++ks_)                                                 \
            DST[n_][ks_] = *(const s8v*)((const char*)&ldsB[BUF][0] + row * 128 +         \
                                         ((ks_*64 + kcol) ^ swz));                        \
    } } while (0)
#define MFMA_Q(MH, NH, BF) do {                                                           \
    __builtin_amdgcn_s_setprio(1);                                                        \
    _Pragma("unroll")                                                                     \
    for (int m_ = 0; m_ < 4; ++m_)                                                        \
    _Pragma("unroll")                                                                     \
    for (int n_ = 0; n_ < 2; ++n_)                                                        \
    _Pragma("unroll")                                                                     \
    for (int ks_ = 0; ks_ < 2; ++ks_)                                                     \
        acc[(MH)*4 + m_][(NH)*2 + n_] = __builtin_amdgcn_mfma_f32_16x16x32_bf16(          \
            af[m_][ks_], BF[n_][ks_], acc[(MH)*4 + m_][(NH)*2 + n_], 0, 0, 0);            \
    __builtin_amdgcn_s_setprio(0);                                                        \
} while (0)
#define MEMBAR asm volatile("" ::: "memory")
#define BAR() do { MEMBAR; __builtin_amdgcn_s_barrier(); MEMBAR; } while (0)
#define WAITLGKM0() do { asm volatile("s_waitcnt lgkmcnt(0)" ::: "memory");               \
                         __builtin_amdgcn_sched_barrier(0); } while (0)

    const int kTiles = K >> 6;
    STAGE_HA(0, 0, 0); STAGE_HB(0, 0, 0); STAGE_HB(0, 0, 1); STAGE_HA(0, 0, 1);
    STAGE_HA(1, 1, 0); STAGE_HB(1, 1, 0); STAGE_HB(1, 1, 1); STAGE_HA(1, 1, 1);
    asm volatile("s_waitcnt vmcnt(6)" ::: "memory");
    BAR();

    for (int kt = 0; kt < kTiles; ++kt) {
        const int buf = kt & 1;
        const bool pf = (kt + 2 < kTiles);
        READ_A(buf, 0); READ_B(buf, 0, bfA);
        asm volatile("s_waitcnt lgkmcnt(8)" ::: "memory");
        BAR(); WAITLGKM0();
        MFMA_Q(0, 0, bfA);
        BAR();
        READ_B(buf, 1, bfB);
        if (pf) STAGE_HA(buf, kt + 2, 0);
        BAR(); WAITLGKM0();
        MFMA_Q(0, 1, bfB);
        BAR();
        READ_A(buf, 1);
        if (pf) STAGE_HB(buf, kt + 2, 0);
        BAR(); WAITLGKM0();
        MFMA_Q(1, 1, bfB);
        BAR();
        if (pf) { STAGE_HB(buf, kt + 2, 1); STAGE_HA(buf, kt + 2, 1); }
        MFMA_Q(1, 0, bfA);
        if (pf) asm volatile("s_waitcnt vmcnt(8)" ::: "memory");
        else    asm volatile("s_waitcnt vmcnt(0)" ::: "memory");
        BAR();
    }

    if (EPI == 0) {
        // (unused in this round)
    } else {
        int h = (n0 >> 2) + wc * 16 + (lane & 15);
        float bv[4];
#pragma unroll
        for (int j = 0; j < 4; ++j)
            bv[j] = bias[n0 + (j >> 1) * 128 + wc * 32 + (j & 1) * 16 + (lane & 15)];
#pragma unroll
        for (int mh = 0; mh < 2; ++mh)
#pragma unroll
        for (int m = 0; m < 4; ++m) {
            int rb = m0 + mh * 128 + wr * 64 + m * 16 + ((lane >> 4) << 2);
#pragma unroll
            for (int r = 0; r < 4; ++r) {
                int b = rb + r;
                float pf_ = acc[mh * 4 + m][0][r] + bv[0];
                float pi_ = acc[mh * 4 + m][1][r] + bv[1];
                float pc_ = acc[mh * 4 + m][2][r] + bv[2];
                float po_ = acc[mh * 4 + m][3][r] + bv[3];
                float fg = 1.f / (1.f + __expf(-pf_));
                float ig = 1.f / (1.f + __expf(-pi_));
                float gg = tanhf(pc_);
                float og = 1.f / (1.f + __expf(-po_));
                size_t off = (size_t)b * H_DIM + h;
                float nc = fg * cell[off] + ig * gg;
                float nh = og * tanhf(nc);
                outC[off] = nc;
                outH[off] = nh;
                hidF8[off] = f2fp8(nh * 8.0f);   // A-operand pre-scale 2^3 (MFMA scale 2^-3)
            }
        }
    }
#undef GLOAD
#undef STAGE_HA
#undef STAGE_HB
#undef READ_A
#undef READ_B
#undef MFMA_Q
#undef MEMBAR
#undef BAR
#undef WAITLGKM0
}

// ---------------- head GEMM: MX-fp8, 128x128 tile, BK=128, 2-phase m97 structure ----------------
// A = hid fp8 (pre-scaled x8), Bt = WendT fp8 (pre-scaled x32); fixed E8M0 scales 124/122.
// Fused: bias add, fp32 logit store, per-row (max,sumexp) partials.
__global__ __launch_bounds__(256, 3)
void k_gemm_mx(const uint8_t* __restrict__ A, const uint8_t* __restrict__ Bt,
               float* __restrict__ C, const float* __restrict__ bias,
               float2* __restrict__ partials, int N, int K, int ldc, int ncb) {
    __shared__ __align__(16) uint8_t ldsA[128 * 128];   // 16 KB
    __shared__ __align__(16) uint8_t ldsB[128 * 128];   // 16 KB
    const int t = threadIdx.x;
    const int wid = t >> 6, lane = t & 63;
    const int wrr = wid >> 1, wcc = wid & 1;            // 2x2 waves, each 64x64 output

    int nwg = gridDim.x, bid = blockIdx.x;
    int wg = (bid & 7) * (nwg >> 3) + (bid >> 3);       // XCD swizzle (grid %8==0)
    int NT = N >> 7;                                     // 250
    int mt = wg / NT, nt = wg - mt * NT;
    int m0 = mt << 7, n0 = nt << 7;

    // staging: idx = c*256+t -> row=idx>>3 (128 rows x 8 chunks of 16B); source pre-swizzled
    int offA[4], offB[4];
#pragma unroll
    for (int c = 0; c < 4; ++c) {
        int idx = c * 256 + t;
        int row = idx >> 3;
        int cb  = ((idx & 7) ^ (row & 7)) << 4;
        offA[c] = (m0 + row) * K + cb;
        offB[c] = (n0 + row) * K + cb;
    }

    f16v acc[2][2];
#pragma unroll
    for (int i = 0; i < 2; ++i)
#pragma unroll
        for (int j = 0; j < 2; ++j)
#pragma unroll
            for (int r = 0; r < 16; ++r) acc[i][j][r] = 0.f;

    const int lr32 = lane & 31;
    const int kh   = (lane >> 5) << 5;   // 0 or 32: k-half within K=64

    const int kTiles = K >> 7;           // 16
    for (int kt = 0; kt < kTiles; ++kt) {
#pragma unroll
        for (int c = 0; c < 4; ++c) {
            __builtin_amdgcn_global_load_lds(
                (const __attribute__((address_space(1))) void*)(A + offA[c] + (kt << 7)),
                (__attribute__((address_space(3))) void*)&ldsA[(c * 256 + wid * 64) * 16], 16, 0, 0);
            __builtin_amdgcn_global_load_lds(
                (const __attribute__((address_space(1))) void*)(Bt + offB[c] + (kt << 7)),
                (__attribute__((address_space(3))) void*)&ldsB[(c * 256 + wid * 64) * 16], 16, 0, 0);
        }
        __syncthreads();

#pragma unroll
        for (int kk = 0; kk < 2; ++kk) {
            i8v af[2], bf[2];
#pragma unroll
            for (int mi = 0; mi < 2; ++mi) {
                int row = wrr * 64 + mi * 32 + lr32;
                int sw = (row & 7) << 4;
                int o0 = (kk * 64 + kh) ^ sw;
                int o1 = (kk * 64 + kh + 16) ^ sw;
                i4v lo = *(const i4v*)&ldsA[row * 128 + o0];
                i4v hi = *(const i4v*)&ldsA[row * 128 + o1];
                af[mi] = __builtin_shufflevector(lo, hi, 0, 1, 2, 3, 4, 5, 6, 7);
            }
#pragma unroll
            for (int ni = 0; ni < 2; ++ni) {
                int row = wcc * 64 + ni * 32 + lr32;
                int sw = (row & 7) << 4;
                int o0 = (kk * 64 + kh) ^ sw;
                int o1 = (kk * 64 + kh + 16) ^ sw;
                i4v lo = *(const i4v*)&ldsB[row * 128 + o0];
                i4v hi = *(const i4v*)&ldsB[row * 128 + o1];
                bf[ni] = __builtin_shufflevector(lo, hi, 0, 1, 2, 3, 4, 5, 6, 7);
            }
#pragma unroll
            for (int mi = 0; mi < 2; ++mi)
#pragma unroll
                for (int ni = 0; ni < 2; ++ni)
                    acc[mi][ni] = __builtin_amdgcn_mfma_scale_f32_32x32x64_f8f6f4(
                        af[mi], bf[ni], acc[mi][ni], 0, 0, 0, 124, 0, 122);
        }
        __syncthreads();
    }

    // epilogue: C/D 32x32 layout: col = lane&31, row = (r&3) + 8*(r>>2) + 4*(lane>>5)
    float bv[2];
    int cg0 = n0 + wcc * 64 + lr32;
    bv[0] = bias[cg0];
    bv[1] = bias[cg0 + 32];
    float2* sm = (float2*)ldsA;          // [2 wcc][128 rows]
#pragma unroll
    for (int mi = 0; mi < 2; ++mi) {
#pragma unroll
        for (int r = 0; r < 16; ++r) {
            int lr = wrr * 64 + mi * 32 + (r & 3) + 8 * (r >> 2) + 4 * (lane >> 5);
            float v0 = acc[mi][0][r] + bv[0];
            float v1 = acc[mi][1][r] + bv[1];
            size_t cr = (size_t)(m0 + lr) * ldc;
            C[cr + cg0] = v0;
            C[cr + cg0 + 32] = v1;
            float mx = fmaxf(v0, v1);
            float ss = __expf(v0 - mx) + __expf(v1 - mx);
#pragma unroll
            for (int off = 1; off < 32; off <<= 1) {
                float mo = __shfl_xor(mx, off);
                float so = __shfl_xor(ss, off);
                float nm = fmaxf(mx, mo);
                ss = ss * __expf(mx - nm) + so * __expf(mo - nm);
                mx = nm;
            }
            if (lr32 == 0) sm[wcc * 128 + lr] = make_float2(mx, ss);
        }
    }
    __syncthreads();
    if (t < 128) {
        float2 a = sm[t], b = sm[128 + t];
        float M = fmaxf(a.x, b.x);
        float S = a.y * __expf(a.x - M) + b.y * __expf(b.x - M);
        partials[(size_t)(m0 + t) * ncb + (n0 >> 7)] = make_float2(M, S);
    }
}

// ---------------- reduce per-block (m,s) partials -> lse[row] ----------------
__global__ void k_lsefin(const float2* __restrict__ part, float* __restrict__ lse, int ncb) {
    int row = blockIdx.x;
    int l = threadIdx.x;   // 64
    float M = -1e30f, S = 0.f;
    for (int i = l; i < ncb; i += 64) {
        float2 p = part[(size_t)row * ncb + i];
        float nm = fmaxf(M, p.x);
        S = S * __expf(M - nm) + p.y * __expf(p.x - nm);
        M = nm;
    }
#pragma unroll
    for (int off = 1; off < 64; off <<= 1) {
        float Mo = __shfl_xor(M, off);
        float So = __shfl_xor(S, off);
        float nm = fmaxf(M, Mo);
        S = S * __expf(M - nm) + So * __expf(Mo - nm);
        M = nm;
    }
    if (l == 0) lse[row] = M + logf(S);
}

__global__ void k_norm(float* __restrict__ out, const float* __restrict__ lse) {
    int i = blockIdx.x * blockDim.x + threadIdx.x;
    int b = i / (V_DIM / 4);
    int c = (i - b * (V_DIM / 4)) * 4;
    float l = lse[b];
    float* p = out + (size_t)b * V_DIM + c;
    float4 v = *(const float4*)p;
    v.x -= l; v.y -= l; v.z -= l; v.w -= l;
    *(float4*)p = v;
}

extern "C" void kernel_launch(void* const* d_in, const int* in_sizes, int n_in,
                              void* d_out, int out_size, void* d_ws, size_t ws_size,
                              hipStream_t stream) {
    const float* in_input  = (const float*)d_in[0];
    const float* in_hidden = (const float*)d_in[1];
    const float* in_cell   = (const float*)d_in[2];
    const float* We   = (const float*)d_in[3];
    const float* be   = (const float*)d_in[4];
    const float* Wf   = (const float*)d_in[5];
    const float* bfv  = (const float*)d_in[6];
    const float* Wi   = (const float*)d_in[7];
    const float* biv  = (const float*)d_in[8];
    const float* Wc   = (const float*)d_in[9];
    const float* bcv  = (const float*)d_in[10];
    const float* Wo   = (const float*)d_in[11];
    const float* bov  = (const float*)d_in[12];
    const float* Uf   = (const float*)d_in[13];
    const float* bhf  = (const float*)d_in[14];
    const float* Ui   = (const float*)d_in[15];
    const float* bhi  = (const float*)d_in[16];
    const float* Uc   = (const float*)d_in[17];
    const float* bhc  = (const float*)d_in[18];
    const float* Uo   = (const float*)d_in[19];
    const float* bho  = (const float*)d_in[20];
    const float* Wend = (const float*)d_in[21];
    const float* bend = (const float*)d_in[22];

    char* ws = (char*)d_ws;
    const size_t oWendF8 = 0;                                    // 32000*2048   = 65,536,000
    const size_t oHidF8  = oWendF8 + (size_t)V_DIM * H_DIM;      // 4096*2048    =  8,388,608
    const size_t oBias2  = oHidF8 + (size_t)B_DIM * H_DIM;       // 32,768
    const size_t oLse    = oBias2 + 4 * H_DIM * 4;               // 16,384
    const size_t oPart   = oLse + B_DIM * 4;                     // 4096*250*8   =  8,192,000
    const size_t oAin    = oPart + (size_t)B_DIM * 250 * 8;      // 33,554,432
    const size_t oWeT    = oAin + (size_t)B_DIM * DIN * 2;       // 16,777,216
    const size_t oA2     = oWeT + (size_t)E_DIM * DIN * 2;       // 33,554,432
    const size_t oWUT    = oA2  + (size_t)B_DIM * 4096 * 2;      // 67,108,864

    uint8_t* WendF8 = (uint8_t*)(ws + oWendF8);
    uint8_t* hidF8  = (uint8_t*)(ws + oHidF8);
    float*   bias2  = (float*)(ws + oBias2);
    float*   lse    = (float*)(ws + oLse);
    float2*  part   = (float2*)(ws + oPart);
    ushort*  Ain    = (ushort*)(ws + oAin);
    ushort*  WeT    = (ushort*)(ws + oWeT);
    ushort*  A2     = (ushort*)(ws + oA2);
    ushort*  WUT    = (ushort*)(ws + oWUT);

    float* out  = (float*)d_out;
    float* outH = out + (size_t)B_DIM * V_DIM;
    float* outC = outH + (size_t)B_DIM * H_DIM;

    const int NCB = V_DIM / 128;   // 250

    dim3 blk256(256), blk512(512), blk64(64);

    // P0: convert input + hidden, transpose all weights, pack biases
    k_cvt<<<dim3((B_DIM * DIN / 4) / 256), blk256, 0, stream>>>(in_input, Ain, B_DIM * DIN / 4);
    k_cvt_hidden<<<dim3((B_DIM * H_DIM / 4) / 256), blk256, 0, stream>>>(in_hidden, A2);

    dim3 tb(32, 8);
    k_transpose_bf16<<<dim3(E_DIM / 32, DIN / 32), tb, 0, stream>>>(We, WeT, E_DIM, DIN, 0, 0);
    k_transpose_gate<<<dim3(H_DIM / 32, E_DIM / 32), tb, 0, stream>>>(Wf, WUT, 0, 0);
    k_transpose_gate<<<dim3(H_DIM / 32, E_DIM / 32), tb, 0, stream>>>(Wi, WUT, 1, 0);
    k_transpose_gate<<<dim3(H_DIM / 32, E_DIM / 32), tb, 0, stream>>>(Wc, WUT, 2, 0);
    k_transpose_gate<<<dim3(H_DIM / 32, E_DIM / 32), tb, 0, stream>>>(Wo, WUT, 3, 0);
    k_transpose_gate<<<dim3(H_DIM / 32, H_DIM / 32), tb, 0, stream>>>(Uf, WUT, 0, 2048);
    k_transpose_gate<<<dim3(H_DIM / 32, H_DIM / 32), tb, 0, stream>>>(Ui, WUT, 1, 2048);
    k_transpose_gate<<<dim3(H_DIM / 32, H_DIM / 32), tb, 0, stream>>>(Uc, WUT, 2, 2048);
    k_transpose_gate<<<dim3(H_DIM / 32, H_DIM / 32), tb, 0, stream>>>(Uo, WUT, 3, 2048);
    k_transpose_fp8<<<dim3(V_DIM / 32, H_DIM / 32), tb, 0, stream>>>(Wend, WendF8, V_DIM, H_DIM);
    k_biaspack<<<dim3(H_DIM / 256), blk256, 0, stream>>>(bfv, bhf, biv, bhi, bcv, bhc, bov, bho, bias2);

    // P1: emb = input @ We + be -> A2 left half (bf16)
    k_gemm_bt<1><<<dim3((B_DIM / 128) * (E_DIM / 128)), blk256, 0, stream>>>(
        Ain, WeT, A2, be, B_DIM, E_DIM, DIN, DIN, DIN, 4096);

    // P2: gates GEMM + fused LSTM cell -> outH/outC/hidF8
    k_gemm256<2><<<dim3((B_DIM / 256) * (8192 / 256)), blk512, 0, stream>>>(
        A2, WUT, nullptr, bias2, 8192, 4096, 4096, 4096, 0,
        in_cell, outH, outC, hidF8, nullptr, 0);

    // P3: logits = new_hidden @ Wend + bend -> d_out (fp32), MX-fp8, fused row-stat partials
    k_gemm_mx<<<dim3((B_DIM / 128) * (V_DIM / 128)), blk256, 0, stream>>>(
        hidF8, WendF8, out, bend, part, V_DIM, H_DIM, V_DIM, NCB);

    // P4: finish log_softmax
    k_lsefin<<<dim3(B_DIM), blk64, 0, stream>>>(part, lse, NCB);
    k_norm<<<dim3(B_DIM * (V_DIM / 4) / 256), blk256, 0, stream>>>(out, lse);
}